// Round 9
// baseline (442.215 us; speedup 1.0000x reference)
//
#include <hip/hip_runtime.h>
#include <math.h>

namespace {

typedef unsigned short u16;
typedef unsigned int   u32;
using bf16x8 = __attribute__((ext_vector_type(8))) short;
using f32x4  = __attribute__((ext_vector_type(4))) float;

constexpr int T_   = 512;
constexpr int BH   = 32;
constexpr int NLAG = 64;
constexpr int KTOP = 18;

__device__ __forceinline__ int lag_of(int li) { return (li < 63) ? (1 + 7 * li) : 511; }

__device__ __forceinline__ u16 bf16r(float f) {          // RNE fp32 -> bf16
  u32 u = __builtin_bit_cast(u32, f);
  u += 0x7fffu + ((u >> 16) & 1u);
  return (u16)(u >> 16);
}
__device__ __forceinline__ float bf2f(u16 h) {
  u32 u = ((u32)h) << 16;
  return __builtin_bit_cast(float, u);
}

// dword-aligned 16B load at even element pe, returning elements [odd .. odd+7].
__device__ __forceinline__ bf16x8 load_shift8(const u16* pe, int odd) {
  uint4 a = *(const uint4*)(pe);
  union { u32 u[4]; bf16x8 v; } r;
  if (odd) {
    u32 b = *(const u32*)(pe + 8);
    r.u[0] = __builtin_amdgcn_alignbit(a.y, a.x, 16);
    r.u[1] = __builtin_amdgcn_alignbit(a.z, a.y, 16);
    r.u[2] = __builtin_amdgcn_alignbit(a.w, a.z, 16);
    r.u[3] = __builtin_amdgcn_alignbit(b,   a.w, 16);
  } else {
    r.u[0] = a.x; r.u[1] = a.y; r.u[2] = a.z; r.u[3] = a.w;
  }
  return r.v;
}

// ---------------- x -> bf16 hi/lo split ---------------------------------------
__global__ __launch_bounds__(256) void k_prep_x(const float* __restrict__ x,
                                                u16* __restrict__ xh, u16* __restrict__ xl) {
  int i0 = (blockIdx.x * 256 + threadIdx.x) * 4;
  float4 v = *(const float4*)(x + i0);
  float vv[4] = {v.x, v.y, v.z, v.w};
  u16 h[4], lo[4];
#pragma unroll
  for (int e = 0; e < 4; ++e) { h[e] = bf16r(vv[e]); lo[e] = bf16r(vv[e] - bf2f(h[e])); }
  *(ushort4*)(xh + i0) = make_ushort4(h[0], h[1], h[2], h[3]);
  *(ushort4*)(xl + i0) = make_ushort4(lo[0], lo[1], lo[2], lo[3]);
}

// ---------------- W -> W^T bf16 hi/lo (z = q,k,v,o) ---------------------------
__global__ __launch_bounds__(256) void k_prep_w(const float* __restrict__ Wq, const float* __restrict__ Wk,
                                                const float* __restrict__ Wv, const float* __restrict__ Wo,
                                                u16* __restrict__ WTh, u16* __restrict__ WTl) {
  const int z = blockIdx.z;
  const float* W = (z == 0) ? Wq : (z == 1) ? Wk : (z == 2) ? Wv : Wo;
  u16* th = WTh + (size_t)z * 262144;
  u16* tl = WTl + (size_t)z * 262144;
  __shared__ float tile[64][65];
  const int r0 = blockIdx.y * 64, c0 = blockIdx.x * 64;
#pragma unroll
  for (int j = 0; j < 16; ++j) {
    int fid = threadIdx.x + 256 * j;
    int r = fid >> 6, c = fid & 63;
    tile[r][c] = W[(size_t)(r0 + r) * 512 + c0 + c];
  }
  __syncthreads();
#pragma unroll
  for (int j = 0; j < 16; ++j) {
    int fid = threadIdx.x + 256 * j;
    int n = fid >> 6, kk = fid & 63;
    float v = tile[kk][n];
    u16 h = bf16r(v);
    th[(size_t)(c0 + n) * 512 + r0 + kk] = h;
    tl[(size_t)(c0 + n) * 512 + r0 + kk] = bf16r(v - bf2f(h));
  }
}

// ---------------- QKV projection (MFMA, 64-row m-tiles). Q,K split ------------
__global__ __launch_bounds__(256) void k_qkv(const u16* __restrict__ xh, const u16* __restrict__ xl,
                                             const u16* __restrict__ WTh, const u16* __restrict__ WTl,
                                             const float* __restrict__ bq, const float* __restrict__ bk,
                                             const float* __restrict__ bv,
                                             float* __restrict__ qo, float* __restrict__ ko, float* __restrict__ vo) {
  const int z = blockIdx.z;
  const bool split = (z < 2);                     // Q,K feed the top-k scores: fp32-grade
  const u16* Bh_ = WTh + (size_t)z * 262144;
  const u16* Bl_ = WTl + (size_t)z * 262144;
  const float* bias = (z == 0) ? bq : (z == 1) ? bk : bv;
  float* out = (z == 0) ? qo : (z == 1) ? ko : vo;
  const int n0 = blockIdx.x * 64, m0 = blockIdx.y * 64;
  const int l = threadIdx.x & 63, w = threadIdx.x >> 6;
  const int lr = l & 15, lk = (l >> 4) * 8;
  const int arow = m0 + 16 * w + lr;
  f32x4 acc[4];
#pragma unroll
  for (int i = 0; i < 4; ++i) { float b = bias[n0 + 16 * i + lr]; acc[i] = (f32x4){b, b, b, b}; }
  for (int ks = 0; ks < 16; ++ks) {
    const int kb2 = ks * 32 + lk;
    bf16x8 A  = *(const bf16x8*)(xh + (size_t)arow * 512 + kb2);
    bf16x8 Al = {};
    if (split) Al = *(const bf16x8*)(xl + (size_t)arow * 512 + kb2);
#pragma unroll
    for (int i = 0; i < 4; ++i) {
      bf16x8 Bf = *(const bf16x8*)(Bh_ + (size_t)(n0 + 16 * i + lr) * 512 + kb2);
      acc[i] = __builtin_amdgcn_mfma_f32_16x16x32_bf16(A, Bf, acc[i], 0, 0, 0);
      if (split) {
        bf16x8 Bl2 = *(const bf16x8*)(Bl_ + (size_t)(n0 + 16 * i + lr) * 512 + kb2);
        acc[i] = __builtin_amdgcn_mfma_f32_16x16x32_bf16(A, Bl2, acc[i], 0, 0, 0);
        acc[i] = __builtin_amdgcn_mfma_f32_16x16x32_bf16(Al, Bf, acc[i], 0, 0, 0);
      }
    }
  }
#pragma unroll
  for (int i = 0; i < 4; ++i)
#pragma unroll
    for (int r = 0; r < 4; ++r) {
      int m = m0 + 16 * w + (l >> 4) * 4 + r;
      int n = n0 + 16 * i + lr;
      int b_ = m >> 9, t = m & 511, h_ = n >> 6, dh = n & 63;
      out[(((size_t)(b_ * 8 + h_)) * 512 + t) * 64 + dh] = acc[i][r];
    }
}

// ---------------- inverse L2 norms over time for Q and K ----------------------
__global__ __launch_bounds__(256) void k_ssq(const float* __restrict__ qf, const float* __restrict__ kf,
                                             float* __restrict__ sinv) {
  const int bh = blockIdx.x, which = blockIdx.y;
  const float* Xb = (which ? kf : qf) + (size_t)bh * T_ * 64;
  const int tid = threadIdx.x;
  __shared__ float red[256];
  float ss = 0.f;
  for (int i = 0; i < 128; ++i) { float v = Xb[tid + 256 * i]; ss += v * v; }
  red[tid] = ss;
  __syncthreads();
  if (tid < 64) {
    float s = red[tid] + red[tid + 64] + red[tid + 128] + red[tid + 192];
    sinv[which * 2048 + bh * 64 + tid] = 1.0f / sqrtf(fmaxf(s, 1e-8f));
  }
}

// ---------------- pack: Q^T hi/lo, K^T duplicated hi/lo, V duplicated ---------
__global__ __launch_bounds__(256) void k_pack(const float* __restrict__ qf, const float* __restrict__ kf,
                                              const float* __restrict__ vf, const float* __restrict__ sinv,
                                              u16* __restrict__ QTh, u16* __restrict__ QTl,
                                              u16* __restrict__ KTh, u16* __restrict__ KTl,
                                              u16* __restrict__ V2) {
  const int t0 = blockIdx.x * 64, bh = blockIdx.y;
  const int tid = threadIdx.x;
  __shared__ float tile[64][65];
  // ---- Q: normalize, transpose, hi/lo ----
#pragma unroll
  for (int j = 0; j < 16; ++j) {
    int fid = tid + 256 * j;
    int r = fid >> 6, c = fid & 63;
    tile[r][c] = qf[((size_t)bh * 512 + t0 + r) * 64 + c] * sinv[bh * 64 + c];
  }
  __syncthreads();
#pragma unroll
  for (int j = 0; j < 16; ++j) {
    int fid = tid + 256 * j;
    int c = fid >> 6, tl2 = fid & 63;
    float v = tile[tl2][c];
    u16 hh = bf16r(v);
    size_t dst = ((size_t)bh * 64 + c) * 512 + t0 + tl2;
    QTh[dst] = hh;
    QTl[dst] = bf16r(v - bf2f(hh));
  }
  __syncthreads();
  // ---- K: normalize, transpose, duplicate in t, hi/lo ----
#pragma unroll
  for (int j = 0; j < 16; ++j) {
    int fid = tid + 256 * j;
    int r = fid >> 6, c = fid & 63;
    tile[r][c] = kf[((size_t)bh * 512 + t0 + r) * 64 + c] * sinv[2048 + bh * 64 + c];
  }
  __syncthreads();
#pragma unroll
  for (int j = 0; j < 16; ++j) {
    int fid = tid + 256 * j;
    int c = fid >> 6, tl2 = fid & 63;
    float v = tile[tl2][c];
    u16 hh = bf16r(v);
    u16 ll = bf16r(v - bf2f(hh));
    size_t base = ((size_t)bh * 64 + c) * 1024 + t0 + tl2;
    KTh[base] = hh;       KTl[base] = ll;
    KTh[base + 512] = hh; KTl[base + 512] = ll;
  }
  // ---- V: duplicate rows, single bf16, natural layout ----
#pragma unroll
  for (int j = 0; j < 4; ++j) {
    int r = (tid >> 4) + 16 * j, c4 = (tid & 15) * 4;
    float4 v4 = *(const float4*)(vf + ((size_t)bh * 512 + t0 + r) * 64 + c4);
    ushort4 o = make_ushort4(bf16r(v4.x), bf16r(v4.y), bf16r(v4.z), bf16r(v4.w));
    size_t base = ((size_t)bh * 1024 + t0 + r) * 64 + c4;
    *(ushort4*)(V2 + base) = o;
    *(ushort4*)(V2 + base + 512 * 64) = o;
  }
}

// ---------------- lag scores: wave owns 16 d-rows x full K; no spills ---------
// grid 2048: xcd = wg&7 owns bh in [xcd*4, xcd*4+4) -> per-XCD L2 set ~1.25MB
// Per wave: acc[4] (16 VGPR) + A/B frags (~16) -> ~70 VGPR, no LDS reduce.
__global__ __launch_bounds__(256) void k_score(const u16* __restrict__ KTh, const u16* __restrict__ KTl,
                                               const u16* __restrict__ QTh, const u16* __restrict__ QTl,
                                               float* __restrict__ score,
                                               const float* __restrict__ p_lambda) {
  const int wg = blockIdx.x;
  const int xcd = wg & 7, j = wg >> 3;            // j: 0..255
  const int bh = xcd * 4 + (j >> 6);
  const int li = 1 + (j & 63);                    // 1..64
  const int lag = lag_of(li - 1);
  const int tid = threadIdx.x, l = tid & 63, w = tid >> 6;
  const int lr = l & 15, lk = (l >> 4) * 8;
  __shared__ float sred[8];
  const int shift = 512 - lag;
  const int sbase = shift & ~1;
  const int odd = shift & 1;
  const u16* qh = QTh + (size_t)bh * 32768 + (size_t)lr * 512 + lk;
  const u16* ql = QTl + (size_t)bh * 32768 + (size_t)lr * 512 + lk;
  const u16* kh = KTh + (size_t)bh * 65536 + (size_t)(16 * w + lr) * 1024 + lk + sbase;
  const u16* kl = KTl + (size_t)bh * 65536 + (size_t)(16 * w + lr) * 1024 + lk + sbase;
  f32x4 acc[4] = {};
  for (int kk = 0; kk < 16; ++kk) {
    const int o = kk * 32;
    bf16x8 Ah = load_shift8(kh + o, odd);
    bf16x8 Al = load_shift8(kl + o, odd);
#pragma unroll
    for (int ni = 0; ni < 4; ++ni) {
      bf16x8 Bh2 = *(const bf16x8*)(qh + ni * 8192 + o);
      bf16x8 Bl2 = *(const bf16x8*)(ql + ni * 8192 + o);
      acc[ni] = __builtin_amdgcn_mfma_f32_16x16x32_bf16(Ah, Bh2, acc[ni], 0, 0, 0);
      acc[ni] = __builtin_amdgcn_mfma_f32_16x16x32_bf16(Ah, Bl2, acc[ni], 0, 0, 0);
      acc[ni] = __builtin_amdgcn_mfma_f32_16x16x32_bf16(Al, Bh2, acc[ni], 0, 0, 0);
    }
  }
  // labs/ldiag over this wave's 16x64 subtile (d = 16w + (l>>4)*4 + r, c = 16ni + lr)
  float labs = 0.f, ldiag = 0.f;
#pragma unroll
  for (int ni = 0; ni < 4; ++ni)
#pragma unroll
    for (int r = 0; r < 4; ++r) {
      int d = 16 * w + (l >> 4) * 4 + r;
      int c = 16 * ni + lr;
      float vv = acc[ni][r];
      labs += fabsf(vv);
      if (d == c) ldiag += fabsf(vv);
    }
#pragma unroll
  for (int off = 32; off > 0; off >>= 1) {
    labs += __shfl_xor(labs, off);
    ldiag += __shfl_xor(ldiag, off);
  }
  if (l == 0) { sred[w] = labs; sred[4 + w] = ldiag; }
  __syncthreads();
  if (tid == 0) {
    float ta = sred[0] + sred[1] + sred[2] + sred[3];
    float td = sred[4] + sred[5] + sred[6] + sred[7];
    float lam = fminf(fmaxf(p_lambda[0], 0.f), 1.f);
    score[(size_t)bh * NLAG + (li - 1)] = lam * td + (1.f - lam) * (ta - td);
  }
}

// ---------------- top-18: one wave per bh, register-resident argmax -----------
__global__ void k_topk(const float* __restrict__ score, int* __restrict__ sel,
                       float* __restrict__ wgt, const float* __restrict__ p_log_tau_lag) {
  const int bh = blockIdx.x;
  const int lane = threadIdx.x;        // 64 lanes = 1 wave
  float sc = score[(size_t)bh * NLAG + lane];
  float ts[KTOP];
  int ti[KTOP];
#pragma unroll
  for (int k = 0; k < KTOP; ++k) {
    float v = sc;
    int idx = lane;
#pragma unroll
    for (int off = 32; off > 0; off >>= 1) {
      float ov = __shfl_xor(v, off);
      int oi = __shfl_xor(idx, off);
      if (ov > v || (ov == v && oi < idx)) { v = ov; idx = oi; }
    }
    ts[k] = v;
    ti[k] = idx;
    if (lane == idx) sc = -3e38f;      // remove winner (tie -> lowest index, like lax.top_k)
  }
  const float tau_lag = fmaxf(expf(p_log_tau_lag[0]), 1e-4f);
  const float mx = ts[0];
  float e[KTOP];
  float sum = 0.f;
#pragma unroll
  for (int k = 0; k < KTOP; ++k) { e[k] = expf((ts[k] - mx) / tau_lag); sum += e[k]; }
  const float rs = 1.0f / sum;
  if (lane < KTOP) {
    sel[bh * KTOP + lane] = ti[lane];
    wgt[bh * KTOP + lane] = e[lane] * rs;
  }
}

// ---------------- fused recompute cov (19 lags) + softmax, wave-local ---------
// grid 608: xcd = wg&7, 4 bh per XCD. Wave owns 16 d-rows; softmax over c is
// within-wave (4 ni regs x 16 lanes) -> no LDS, no barriers.
__global__ __launch_bounds__(256) void k_covsm(const u16* __restrict__ KTh, const u16* __restrict__ KTl,
                                               const u16* __restrict__ QTh, const u16* __restrict__ QTl,
                                               const int* __restrict__ sel, const float* __restrict__ wgt,
                                               u16* __restrict__ attT,
                                               const float* __restrict__ p_log_tau,
                                               const float* __restrict__ p_beta) {
  const int wg = blockIdx.x;
  const int xcd = wg & 7, j = wg >> 3;            // j: 0..75
  const int bh = xcd * 4 + j / 19;
  const int m  = j % 19;                          // 0 => lag0; 1..18 => top lags
  const int lag = (m == 0) ? 0 : lag_of(sel[bh * KTOP + m - 1] & 63);
  const int tid = threadIdx.x, l = tid & 63, w = tid >> 6;
  const int lr = l & 15, lk = (l >> 4) * 8, g = l >> 4;
  const int shift = 512 - lag;
  const int sbase = shift & ~1;
  const int odd = shift & 1;
  const u16* qh = QTh + (size_t)bh * 32768 + (size_t)lr * 512 + lk;
  const u16* ql = QTl + (size_t)bh * 32768 + (size_t)lr * 512 + lk;
  const u16* kh = KTh + (size_t)bh * 65536 + (size_t)(16 * w + lr) * 1024 + lk + sbase;
  const u16* kl = KTl + (size_t)bh * 65536 + (size_t)(16 * w + lr) * 1024 + lk + sbase;
  f32x4 acc[4] = {};
  for (int kk = 0; kk < 16; ++kk) {
    const int o = kk * 32;
    bf16x8 Ah = load_shift8(kh + o, odd);
    bf16x8 Al = load_shift8(kl + o, odd);
#pragma unroll
    for (int ni = 0; ni < 4; ++ni) {
      bf16x8 Bh2 = *(const bf16x8*)(qh + ni * 8192 + o);
      bf16x8 Bl2 = *(const bf16x8*)(ql + ni * 8192 + o);
      acc[ni] = __builtin_amdgcn_mfma_f32_16x16x32_bf16(Ah, Bh2, acc[ni], 0, 0, 0);
      acc[ni] = __builtin_amdgcn_mfma_f32_16x16x32_bf16(Ah, Bl2, acc[ni], 0, 0, 0);
      acc[ni] = __builtin_amdgcn_mfma_f32_16x16x32_bf16(Al, Bh2, acc[ni], 0, 0, 0);
    }
  }
  // softmax over c per row d (c lives in 4 ni regs x 16 lanes lr), then store
  const float itau = 1.f / fmaxf(expf(p_log_tau[0]), 1e-4f);
  const float beta = fminf(fmaxf(p_beta[0], 0.f), 1.f);
  const float smv = (m == 0) ? (1.f - beta) : (beta * wgt[bh * KTOP + m - 1]);
  u16* th = attT + ((size_t)m * BH + bh) * 4096;
  float ev[4][4];                     // [ni][r]
#pragma unroll
  for (int r = 0; r < 4; ++r) {
    float vmax = acc[0][r];
#pragma unroll
    for (int ni = 1; ni < 4; ++ni) vmax = fmaxf(vmax, acc[ni][r]);
#pragma unroll
    for (int off = 8; off > 0; off >>= 1) vmax = fmaxf(vmax, __shfl_xor(vmax, off));
    float s = 0.f;
#pragma unroll
    for (int ni = 0; ni < 4; ++ni) { ev[ni][r] = expf((acc[ni][r] - vmax) * itau); s += ev[ni][r]; }
#pragma unroll
    for (int off = 8; off > 0; off >>= 1) s += __shfl_xor(s, off);
    float inv = smv / s;
#pragma unroll
    for (int ni = 0; ni < 4; ++ni) ev[ni][r] *= inv;
  }
#pragma unroll
  for (int ni = 0; ni < 4; ++ni) {
    ushort4 o4 = make_ushort4(bf16r(ev[ni][0]), bf16r(ev[ni][1]), bf16r(ev[ni][2]), bf16r(ev[ni][3]));
    *(ushort4*)(th + (size_t)(16 * ni + lr) * 64 + 16 * w + 4 * g) = o4;
  }
}

// ---------------- weighted contrib sum: m-split across waves + LDS reduce -----
__global__ __launch_bounds__(256) void k_contrib(const u16* __restrict__ V2,
                                                 const u16* __restrict__ attT,
                                                 const int* __restrict__ sel,
                                                 u16* __restrict__ oh) {
  const int tt = blockIdx.x;                 // 32-row t-tiles: 0..15
  const int bh = blockIdx.y;
  const int b_ = bh >> 3, h_ = bh & 7;
  const int t0 = tt * 32;
  const int tid = threadIdx.x, l = tid & 63, w = tid >> 6;
  const int lr = l & 15, lk = (l >> 4) * 8;
  __shared__ f32x4 lred[2][512];             // 16 KB
  f32x4 acc[2][4] = {};
  const u16* Vb = V2 + (size_t)bh * 65536;
  const int mstart[5] = {0, 5, 10, 15, 19};
  for (int m = mstart[w]; m < mstart[w + 1]; ++m) {
    const int lag = (m == 0) ? 0 : lag_of(sel[bh * KTOP + m - 1] & 63);
    const u16* ab = attT + ((size_t)m * BH + bh) * 4096;
#pragma unroll
    for (int ks = 0; ks < 2; ++ks) {
      const int kb2 = ks * 32 + lk;
      bf16x8 Bf[4];
#pragma unroll
      for (int ni = 0; ni < 4; ++ni) Bf[ni] = *(const bf16x8*)(ab + (size_t)(16 * ni + lr) * 64 + kb2);
#pragma unroll
      for (int mi = 0; mi < 2; ++mi) {
        const int ub = t0 + 16 * mi + 512 - lag + lr;
        bf16x8 A = *(const bf16x8*)(Vb + (size_t)ub * 64 + kb2);
#pragma unroll
        for (int ni = 0; ni < 4; ++ni)
          acc[mi][ni] = __builtin_amdgcn_mfma_f32_16x16x32_bf16(A, Bf[ni], acc[mi][ni], 0, 0, 0);
      }
    }
  }
  if (w >= 2) {
#pragma unroll
    for (int mi = 0; mi < 2; ++mi)
#pragma unroll
      for (int ni = 0; ni < 4; ++ni) lred[w - 2][(mi * 4 + ni) * 64 + l] = acc[mi][ni];
  }
  __syncthreads();
  if (w < 2) {
#pragma unroll
    for (int mi = 0; mi < 2; ++mi)
#pragma unroll
      for (int ni = 0; ni < 4; ++ni) acc[mi][ni] += lred[w][(mi * 4 + ni) * 64 + l];
  }
  __syncthreads();
  if (w == 1) {
#pragma unroll
    for (int mi = 0; mi < 2; ++mi)
#pragma unroll
      for (int ni = 0; ni < 4; ++ni) lred[0][(mi * 4 + ni) * 64 + l] = acc[mi][ni];
  }
  __syncthreads();
  if (w == 0) {
#pragma unroll
    for (int mi = 0; mi < 2; ++mi)
#pragma unroll
      for (int ni = 0; ni < 4; ++ni) {
        acc[mi][ni] += lred[0][(mi * 4 + ni) * 64 + l];
#pragma unroll
        for (int r = 0; r < 4; ++r) {
          int t = t0 + 16 * mi + (l >> 4) * 4 + r;
          int c = 16 * ni + lr;
          oh[((size_t)b_ * 512 + t) * 512 + h_ * 64 + c] = bf16r(acc[mi][ni][r]);
        }
      }
  }
}

// ---------------- final projection (MFMA, single bf16, 64-row m-tiles) --------
__global__ __launch_bounds__(256) void k_out(const u16* __restrict__ oh,
                                             const u16* __restrict__ WTh,
                                             const float* __restrict__ bo, float* __restrict__ out) {
  const u16* Bh_ = WTh + (size_t)3 * 262144;
  const int n0 = blockIdx.x * 64, m0 = blockIdx.y * 64;
  const int l = threadIdx.x & 63, w = threadIdx.x >> 6;
  const int lr = l & 15, lk = (l >> 4) * 8;
  const int arow = m0 + 16 * w + lr;
  f32x4 acc[4];
#pragma unroll
  for (int i = 0; i < 4; ++i) { float b = bo[n0 + 16 * i + lr]; acc[i] = (f32x4){b, b, b, b}; }
  for (int ks = 0; ks < 16; ++ks) {
    int kb2 = ks * 32 + lk;
    bf16x8 A = *(const bf16x8*)(oh + (size_t)arow * 512 + kb2);
#pragma unroll
    for (int i = 0; i < 4; ++i) {
      bf16x8 Bf = *(const bf16x8*)(Bh_ + (size_t)(n0 + 16 * i + lr) * 512 + kb2);
      acc[i] = __builtin_amdgcn_mfma_f32_16x16x32_bf16(A, Bf, acc[i], 0, 0, 0);
    }
  }
#pragma unroll
  for (int i = 0; i < 4; ++i)
#pragma unroll
    for (int r = 0; r < 4; ++r) {
      int m = m0 + 16 * w + (l >> 4) * 4 + r;
      int n = n0 + 16 * i + lr;
      out[(size_t)m * 512 + n] = acc[i][r];
    }
}

}  // namespace

extern "C" void kernel_launch(void* const* d_in, const int* in_sizes, int n_in,
                              void* d_out, int out_size, void* d_ws, size_t ws_size,
                              hipStream_t stream) {
  (void)in_sizes; (void)n_in; (void)out_size; (void)ws_size;
  const float* x  = (const float*)d_in[0];
  const float* Wq = (const float*)d_in[1];
  const float* bq = (const float*)d_in[2];
  const float* Wk = (const float*)d_in[3];
  const float* bk = (const float*)d_in[4];
  const float* Wv = (const float*)d_in[5];
  const float* bv = (const float*)d_in[6];
  const float* Wo = (const float*)d_in[7];
  const float* bo = (const float*)d_in[8];
  const float* p_log_tau     = (const float*)d_in[9];
  const float* p_lambda      = (const float*)d_in[10];
  const float* p_beta        = (const float*)d_in[11];
  const float* p_log_tau_lag = (const float*)d_in[12];

  char* ws = (char*)d_ws;
  const size_t MB = 1ull << 20;
  u16*   xh    = (u16*)(ws + 0 * MB);     // 2 MB
  u16*   xl    = (u16*)(ws + 2 * MB);     // 2 MB
  u16*   WTh   = (u16*)(ws + 4 * MB);     // 2 MB (q,k,v,o)
  u16*   WTl   = (u16*)(ws + 6 * MB);     // 2 MB
  u16*   QTh   = (u16*)(ws + 8 * MB);     // 2 MB  [bh][64][512]
  u16*   QTl   = (u16*)(ws + 10 * MB);    // 2 MB
  u16*   KTh   = (u16*)(ws + 12 * MB);    // 4 MB  [bh][64][1024] t-duplicated
  u16*   KTl   = (u16*)(ws + 16 * MB);    // 4 MB
  u16*   V2    = (u16*)(ws + 20 * MB);    // 4 MB  [bh][1024][64]
  float* qf    = (float*)(ws + 24 * MB);  // 4 MB (dead after k_pack)
  float* kf    = (float*)(ws + 28 * MB);  // 4 MB (dead after k_pack)
  float* vf    = (float*)(ws + 32 * MB);  // 4 MB (dead after k_pack)
  u16*   attT  = (u16*)(ws + 24 * MB);    // 4.75 MB overlay on qf/kf (after k_pack)
  u16*   oh    = (u16*)(ws + 32 * MB);    // 2 MB overlay on vf (after k_pack)
  float* score = (float*)(ws + 70 * MB);          // 8 KB
  float* wgt   = (float*)(ws + 70 * MB + 16384);  // 2.3 KB
  int*   sel   = (int*)(ws + 70 * MB + 32768);    // 2.3 KB
  float* sinv  = (float*)(ws + 70 * MB + 49152);  // 16 KB [2][32][64]

  const dim3 blk(256);

  k_prep_x<<<dim3(1024), blk, 0, stream>>>(x, xh, xl);
  k_prep_w<<<dim3(8, 8, 4), blk, 0, stream>>>(Wq, Wk, Wv, Wo, WTh, WTl);
  k_qkv<<<dim3(8, 32, 3), blk, 0, stream>>>(xh, xl, WTh, WTl, bq, bk, bv, qf, kf, vf);
  k_ssq<<<dim3(32, 2), blk, 0, stream>>>(qf, kf, sinv);
  k_pack<<<dim3(8, 32), blk, 0, stream>>>(qf, kf, vf, sinv, QTh, QTl, KTh, KTl, V2);
  k_score<<<dim3(2048), blk, 0, stream>>>(KTh, KTl, QTh, QTl, score, p_lambda);
  k_topk<<<dim3(32), dim3(64), 0, stream>>>(score, sel, wgt, p_log_tau_lag);
  k_covsm<<<dim3(608), blk, 0, stream>>>(KTh, KTl, QTh, QTl, sel, wgt, attT, p_log_tau, p_beta);
  k_contrib<<<dim3(16, 32), blk, 0, stream>>>(V2, attT, sel, oh);
  k_out<<<dim3(8, 32), blk, 0, stream>>>(oh, WTh, bo, (float*)d_out);
}

// Round 10
// 319.470 us; speedup vs baseline: 1.3842x; 1.3842x over previous
//
#include <hip/hip_runtime.h>
#include <math.h>

namespace {

typedef unsigned short u16;
typedef unsigned int   u32;
using bf16x8 = __attribute__((ext_vector_type(8))) short;
using f32x4  = __attribute__((ext_vector_type(4))) float;

constexpr int T_   = 512;
constexpr int BH   = 32;
constexpr int NLAG = 64;
constexpr int KTOP = 18;

__device__ __forceinline__ int lag_of(int li) { return (li < 63) ? (1 + 7 * li) : 511; }

__device__ __forceinline__ u16 bf16r(float f) {          // RNE fp32 -> bf16
  u32 u = __builtin_bit_cast(u32, f);
  u += 0x7fffu + ((u >> 16) & 1u);
  return (u16)(u >> 16);
}
__device__ __forceinline__ float bf2f(u16 h) {
  u32 u = ((u32)h) << 16;
  return __builtin_bit_cast(float, u);
}

// dword-aligned 16B load at even element pe, returning elements [odd .. odd+7].
__device__ __forceinline__ bf16x8 load_shift8(const u16* pe, int odd) {
  uint4 a = *(const uint4*)(pe);
  union { u32 u[4]; bf16x8 v; } r;
  if (odd) {
    u32 b = *(const u32*)(pe + 8);
    r.u[0] = __builtin_amdgcn_alignbit(a.y, a.x, 16);
    r.u[1] = __builtin_amdgcn_alignbit(a.z, a.y, 16);
    r.u[2] = __builtin_amdgcn_alignbit(a.w, a.z, 16);
    r.u[3] = __builtin_amdgcn_alignbit(b,   a.w, 16);
  } else {
    r.u[0] = a.x; r.u[1] = a.y; r.u[2] = a.z; r.u[3] = a.w;
  }
  return r.v;
}

// ---------------- x -> bf16 hi/lo split ---------------------------------------
__global__ __launch_bounds__(256) void k_prep_x(const float* __restrict__ x,
                                                u16* __restrict__ xh, u16* __restrict__ xl) {
  int i0 = (blockIdx.x * 256 + threadIdx.x) * 4;
  float4 v = *(const float4*)(x + i0);
  float vv[4] = {v.x, v.y, v.z, v.w};
  u16 h[4], lo[4];
#pragma unroll
  for (int e = 0; e < 4; ++e) { h[e] = bf16r(vv[e]); lo[e] = bf16r(vv[e] - bf2f(h[e])); }
  *(ushort4*)(xh + i0) = make_ushort4(h[0], h[1], h[2], h[3]);
  *(ushort4*)(xl + i0) = make_ushort4(lo[0], lo[1], lo[2], lo[3]);
}

// ---------------- W -> W^T bf16 hi/lo (z = q,k,v,o) ---------------------------
__global__ __launch_bounds__(256) void k_prep_w(const float* __restrict__ Wq, const float* __restrict__ Wk,
                                                const float* __restrict__ Wv, const float* __restrict__ Wo,
                                                u16* __restrict__ WTh, u16* __restrict__ WTl) {
  const int z = blockIdx.z;
  const float* W = (z == 0) ? Wq : (z == 1) ? Wk : (z == 2) ? Wv : Wo;
  u16* th = WTh + (size_t)z * 262144;
  u16* tl = WTl + (size_t)z * 262144;
  __shared__ float tile[64][65];
  const int r0 = blockIdx.y * 64, c0 = blockIdx.x * 64;
#pragma unroll
  for (int j = 0; j < 16; ++j) {
    int fid = threadIdx.x + 256 * j;
    int r = fid >> 6, c = fid & 63;
    tile[r][c] = W[(size_t)(r0 + r) * 512 + c0 + c];
  }
  __syncthreads();
#pragma unroll
  for (int j = 0; j < 16; ++j) {
    int fid = threadIdx.x + 256 * j;
    int n = fid >> 6, kk = fid & 63;
    float v = tile[kk][n];
    u16 h = bf16r(v);
    th[(size_t)(c0 + n) * 512 + r0 + kk] = h;
    tl[(size_t)(c0 + n) * 512 + r0 + kk] = bf16r(v - bf2f(h));
  }
}

// ---------------- QKV projection (MFMA, 64-row m-tiles). Q,K split ------------
__global__ __launch_bounds__(256) void k_qkv(const u16* __restrict__ xh, const u16* __restrict__ xl,
                                             const u16* __restrict__ WTh, const u16* __restrict__ WTl,
                                             const float* __restrict__ bq, const float* __restrict__ bk,
                                             const float* __restrict__ bv,
                                             float* __restrict__ qo, float* __restrict__ ko, float* __restrict__ vo) {
  const int z = blockIdx.z;
  const bool split = (z < 2);                     // Q,K feed the top-k scores: fp32-grade
  const u16* Bh_ = WTh + (size_t)z * 262144;
  const u16* Bl_ = WTl + (size_t)z * 262144;
  const float* bias = (z == 0) ? bq : (z == 1) ? bk : bv;
  float* out = (z == 0) ? qo : (z == 1) ? ko : vo;
  const int n0 = blockIdx.x * 64, m0 = blockIdx.y * 64;
  const int l = threadIdx.x & 63, w = threadIdx.x >> 6;
  const int lr = l & 15, lk = (l >> 4) * 8;
  const int arow = m0 + 16 * w + lr;
  f32x4 acc[4];
#pragma unroll
  for (int i = 0; i < 4; ++i) { float b = bias[n0 + 16 * i + lr]; acc[i] = (f32x4){b, b, b, b}; }
  for (int ks = 0; ks < 16; ++ks) {
    const int kb2 = ks * 32 + lk;
    bf16x8 A  = *(const bf16x8*)(xh + (size_t)arow * 512 + kb2);
    bf16x8 Al = {};
    if (split) Al = *(const bf16x8*)(xl + (size_t)arow * 512 + kb2);
#pragma unroll
    for (int i = 0; i < 4; ++i) {
      bf16x8 Bf = *(const bf16x8*)(Bh_ + (size_t)(n0 + 16 * i + lr) * 512 + kb2);
      acc[i] = __builtin_amdgcn_mfma_f32_16x16x32_bf16(A, Bf, acc[i], 0, 0, 0);
      if (split) {
        bf16x8 Bl2 = *(const bf16x8*)(Bl_ + (size_t)(n0 + 16 * i + lr) * 512 + kb2);
        acc[i] = __builtin_amdgcn_mfma_f32_16x16x32_bf16(A, Bl2, acc[i], 0, 0, 0);
        acc[i] = __builtin_amdgcn_mfma_f32_16x16x32_bf16(Al, Bf, acc[i], 0, 0, 0);
      }
    }
  }
#pragma unroll
  for (int i = 0; i < 4; ++i)
#pragma unroll
    for (int r = 0; r < 4; ++r) {
      int m = m0 + 16 * w + (l >> 4) * 4 + r;
      int n = n0 + 16 * i + lr;
      int b_ = m >> 9, t = m & 511, h_ = n >> 6, dh = n & 63;
      out[(((size_t)(b_ * 8 + h_)) * 512 + t) * 64 + dh] = acc[i][r];
    }
}

// ---------------- inverse L2 norms over time for Q and K ----------------------
__global__ __launch_bounds__(256) void k_ssq(const float* __restrict__ qf, const float* __restrict__ kf,
                                             float* __restrict__ sinv) {
  const int bh = blockIdx.x, which = blockIdx.y;
  const float* Xb = (which ? kf : qf) + (size_t)bh * T_ * 64;
  const int tid = threadIdx.x;
  __shared__ float red[256];
  float ss = 0.f;
  for (int i = 0; i < 128; ++i) { float v = Xb[tid + 256 * i]; ss += v * v; }
  red[tid] = ss;
  __syncthreads();
  if (tid < 64) {
    float s = red[tid] + red[tid + 64] + red[tid + 128] + red[tid + 192];
    sinv[which * 2048 + bh * 64 + tid] = 1.0f / sqrtf(fmaxf(s, 1e-8f));
  }
}

// ---------------- pack: Q^T hi/lo, K^T duplicated hi/lo, V duplicated ---------
__global__ __launch_bounds__(256) void k_pack(const float* __restrict__ qf, const float* __restrict__ kf,
                                              const float* __restrict__ vf, const float* __restrict__ sinv,
                                              u16* __restrict__ QTh, u16* __restrict__ QTl,
                                              u16* __restrict__ KTh, u16* __restrict__ KTl,
                                              u16* __restrict__ V2) {
  const int t0 = blockIdx.x * 64, bh = blockIdx.y;
  const int tid = threadIdx.x;
  __shared__ float tile[64][65];
  // ---- Q: normalize, transpose, hi/lo ----
#pragma unroll
  for (int j = 0; j < 16; ++j) {
    int fid = tid + 256 * j;
    int r = fid >> 6, c = fid & 63;
    tile[r][c] = qf[((size_t)bh * 512 + t0 + r) * 64 + c] * sinv[bh * 64 + c];
  }
  __syncthreads();
#pragma unroll
  for (int j = 0; j < 16; ++j) {
    int fid = tid + 256 * j;
    int c = fid >> 6, tl2 = fid & 63;
    float v = tile[tl2][c];
    u16 hh = bf16r(v);
    size_t dst = ((size_t)bh * 64 + c) * 512 + t0 + tl2;
    QTh[dst] = hh;
    QTl[dst] = bf16r(v - bf2f(hh));
  }
  __syncthreads();
  // ---- K: normalize, transpose, duplicate in t, hi/lo ----
#pragma unroll
  for (int j = 0; j < 16; ++j) {
    int fid = tid + 256 * j;
    int r = fid >> 6, c = fid & 63;
    tile[r][c] = kf[((size_t)bh * 512 + t0 + r) * 64 + c] * sinv[2048 + bh * 64 + c];
  }
  __syncthreads();
#pragma unroll
  for (int j = 0; j < 16; ++j) {
    int fid = tid + 256 * j;
    int c = fid >> 6, tl2 = fid & 63;
    float v = tile[tl2][c];
    u16 hh = bf16r(v);
    u16 ll = bf16r(v - bf2f(hh));
    size_t base = ((size_t)bh * 64 + c) * 1024 + t0 + tl2;
    KTh[base] = hh;       KTl[base] = ll;
    KTh[base + 512] = hh; KTl[base + 512] = ll;
  }
  // ---- V: duplicate rows, single bf16, natural layout ----
#pragma unroll
  for (int j = 0; j < 4; ++j) {
    int r = (tid >> 4) + 16 * j, c4 = (tid & 15) * 4;
    float4 v4 = *(const float4*)(vf + ((size_t)bh * 512 + t0 + r) * 64 + c4);
    ushort4 o = make_ushort4(bf16r(v4.x), bf16r(v4.y), bf16r(v4.z), bf16r(v4.w));
    size_t base = ((size_t)bh * 1024 + t0 + r) * 64 + c4;
    *(ushort4*)(V2 + base) = o;
    *(ushort4*)(V2 + base + 512 * 64) = o;
  }
}

// ---------------- lag scores (round-8 structure, no VGPR cap) -----------------
// grid 2048: xcd = wg&7 owns bh in [xcd*4, xcd*4+4). 4-way K-split per block,
// acc[4][4] in registers (~110 VGPR, launch_bounds(256,2) -> no spill).
__global__ __launch_bounds__(256, 2) void k_score(const u16* __restrict__ KTh, const u16* __restrict__ KTl,
                                                  const u16* __restrict__ QTh, const u16* __restrict__ QTl,
                                                  float* __restrict__ score,
                                                  const float* __restrict__ p_lambda) {
  const int wg = blockIdx.x;
  const int xcd = wg & 7, j = wg >> 3;            // j: 0..255
  const int bh = xcd * 4 + (j >> 6);
  const int li = 1 + (j & 63);                    // 1..64
  const int lag = lag_of(li - 1);
  const int tid = threadIdx.x, l = tid & 63, w = tid >> 6;
  const int lr = l & 15, lk = (l >> 4) * 8;
  __shared__ f32x4 lred[2][1024];                 // 32 KB
  const int shift = 512 - lag;
  const int sbase = shift & ~1;
  const int odd = shift & 1;
  const u16* qh = QTh + (size_t)bh * 32768 + (size_t)lr * 512 + w * 128 + lk;
  const u16* ql = QTl + (size_t)bh * 32768 + (size_t)lr * 512 + w * 128 + lk;
  const u16* kh = KTh + (size_t)bh * 65536 + (size_t)lr * 1024 + w * 128 + lk + sbase;
  const u16* kl = KTl + (size_t)bh * 65536 + (size_t)lr * 1024 + w * 128 + lk + sbase;
  f32x4 acc[4][4] = {};
#pragma unroll
  for (int kk = 0; kk < 4; ++kk) {
    const int o = kk * 32;
    bf16x8 Bh2[4], Bl2[4];
#pragma unroll
    for (int ni = 0; ni < 4; ++ni) {
      Bh2[ni] = *(const bf16x8*)(qh + ni * 8192 + o);
      Bl2[ni] = *(const bf16x8*)(ql + ni * 8192 + o);
    }
#pragma unroll
    for (int mi = 0; mi < 4; ++mi) {
      bf16x8 Ah = load_shift8(kh + mi * 16384 + o, odd);
      bf16x8 Al = load_shift8(kl + mi * 16384 + o, odd);
#pragma unroll
      for (int ni = 0; ni < 4; ++ni) {
        acc[mi][ni] = __builtin_amdgcn_mfma_f32_16x16x32_bf16(Ah, Bh2[ni], acc[mi][ni], 0, 0, 0);
        acc[mi][ni] = __builtin_amdgcn_mfma_f32_16x16x32_bf16(Ah, Bl2[ni], acc[mi][ni], 0, 0, 0);
        acc[mi][ni] = __builtin_amdgcn_mfma_f32_16x16x32_bf16(Al, Bh2[ni], acc[mi][ni], 0, 0, 0);
      }
    }
  }
  if (w >= 2) {
#pragma unroll
    for (int mi = 0; mi < 4; ++mi)
#pragma unroll
      for (int ni = 0; ni < 4; ++ni) lred[w - 2][(mi * 4 + ni) * 64 + l] = acc[mi][ni];
  }
  __syncthreads();
  if (w < 2) {
#pragma unroll
    for (int mi = 0; mi < 4; ++mi)
#pragma unroll
      for (int ni = 0; ni < 4; ++ni) acc[mi][ni] += lred[w][(mi * 4 + ni) * 64 + l];
  }
  __syncthreads();
  if (w == 1) {
#pragma unroll
    for (int mi = 0; mi < 4; ++mi)
#pragma unroll
      for (int ni = 0; ni < 4; ++ni) lred[0][(mi * 4 + ni) * 64 + l] = acc[mi][ni];
  }
  __syncthreads();
  if (w == 0) {
    float labs = 0.f, ldiag = 0.f;
#pragma unroll
    for (int mi = 0; mi < 4; ++mi)
#pragma unroll
      for (int ni = 0; ni < 4; ++ni) {
        acc[mi][ni] += lred[0][(mi * 4 + ni) * 64 + l];
#pragma unroll
        for (int r = 0; r < 4; ++r) {
          int d = 16 * mi + (l >> 4) * 4 + r;
          int c = 16 * ni + lr;
          float vv = acc[mi][ni][r];
          labs += fabsf(vv);
          if (d == c) ldiag += fabsf(vv);
        }
      }
#pragma unroll
    for (int off = 32; off > 0; off >>= 1) {
      labs += __shfl_xor(labs, off);
      ldiag += __shfl_xor(ldiag, off);
    }
    if (l == 0) {
      float lam = fminf(fmaxf(p_lambda[0], 0.f), 1.f);
      score[(size_t)bh * NLAG + (li - 1)] = lam * ldiag + (1.f - lam) * (labs - ldiag);
    }
  }
}

// ---------------- top-18: one wave per bh, register-resident argmax -----------
__global__ void k_topk(const float* __restrict__ score, int* __restrict__ sel,
                       float* __restrict__ wgt, const float* __restrict__ p_log_tau_lag) {
  const int bh = blockIdx.x;
  const int lane = threadIdx.x;        // 64 lanes = 1 wave
  float sc = score[(size_t)bh * NLAG + lane];
  float ts[KTOP];
  int ti[KTOP];
#pragma unroll
  for (int k = 0; k < KTOP; ++k) {
    float v = sc;
    int idx = lane;
#pragma unroll
    for (int off = 32; off > 0; off >>= 1) {
      float ov = __shfl_xor(v, off);
      int oi = __shfl_xor(idx, off);
      if (ov > v || (ov == v && oi < idx)) { v = ov; idx = oi; }
    }
    ts[k] = v;
    ti[k] = idx;
    if (lane == idx) sc = -3e38f;      // remove winner (tie -> lowest index, like lax.top_k)
  }
  const float tau_lag = fmaxf(expf(p_log_tau_lag[0]), 1e-4f);
  const float mx = ts[0];
  float e[KTOP];
  float sum = 0.f;
#pragma unroll
  for (int k = 0; k < KTOP; ++k) { e[k] = expf((ts[k] - mx) / tau_lag); sum += e[k]; }
  const float rs = 1.0f / sum;
  if (lane < KTOP) {
    sel[bh * KTOP + lane] = ti[lane];
    wgt[bh * KTOP + lane] = e[lane] * rs;
  }
}

// ---------------- fused recompute cov (19 lags) + softmax (round-8 structure) -
// grid 608: xcd = wg&7, 4 bh per XCD (L2-hot Q/K). launch_bounds(256,2).
__global__ __launch_bounds__(256, 2) void k_covsm(const u16* __restrict__ KTh, const u16* __restrict__ KTl,
                                                  const u16* __restrict__ QTh, const u16* __restrict__ QTl,
                                                  const int* __restrict__ sel, const float* __restrict__ wgt,
                                                  u16* __restrict__ attT,
                                                  const float* __restrict__ p_log_tau,
                                                  const float* __restrict__ p_beta) {
  const int wg = blockIdx.x;
  const int xcd = wg & 7, j = wg >> 3;            // j: 0..75
  const int bh = xcd * 4 + j / 19;
  const int m  = j % 19;                          // 0 => lag0; 1..18 => top lags
  const int lag = (m == 0) ? 0 : lag_of(sel[bh * KTOP + m - 1] & 63);
  const int tid = threadIdx.x, l = tid & 63, w = tid >> 6;
  const int lr = l & 15, lk = (l >> 4) * 8, g = l >> 4;
  __shared__ f32x4 lred[2][1024];                 // 32 KB
  const int shift = 512 - lag;
  const int sbase = shift & ~1;
  const int odd = shift & 1;
  const u16* qh = QTh + (size_t)bh * 32768 + (size_t)lr * 512 + w * 128 + lk;
  const u16* ql = QTl + (size_t)bh * 32768 + (size_t)lr * 512 + w * 128 + lk;
  const u16* kh = KTh + (size_t)bh * 65536 + (size_t)lr * 1024 + w * 128 + lk + sbase;
  const u16* kl = KTl + (size_t)bh * 65536 + (size_t)lr * 1024 + w * 128 + lk + sbase;
  f32x4 acc[4][4] = {};
#pragma unroll
  for (int kk = 0; kk < 4; ++kk) {
    const int o = kk * 32;
    bf16x8 Bh2[4], Bl2[4];
#pragma unroll
    for (int ni = 0; ni < 4; ++ni) {
      Bh2[ni] = *(const bf16x8*)(qh + ni * 8192 + o);
      Bl2[ni] = *(const bf16x8*)(ql + ni * 8192 + o);
    }
#pragma unroll
    for (int mi = 0; mi < 4; ++mi) {
      bf16x8 Ah = load_shift8(kh + mi * 16384 + o, odd);
      bf16x8 Al = load_shift8(kl + mi * 16384 + o, odd);
#pragma unroll
      for (int ni = 0; ni < 4; ++ni) {
        acc[mi][ni] = __builtin_amdgcn_mfma_f32_16x16x32_bf16(Ah, Bh2[ni], acc[mi][ni], 0, 0, 0);
        acc[mi][ni] = __builtin_amdgcn_mfma_f32_16x16x32_bf16(Ah, Bl2[ni], acc[mi][ni], 0, 0, 0);
        acc[mi][ni] = __builtin_amdgcn_mfma_f32_16x16x32_bf16(Al, Bh2[ni], acc[mi][ni], 0, 0, 0);
      }
    }
  }
  if (w >= 2) {
#pragma unroll
    for (int mi = 0; mi < 4; ++mi)
#pragma unroll
      for (int ni = 0; ni < 4; ++ni) lred[w - 2][(mi * 4 + ni) * 64 + l] = acc[mi][ni];
  }
  __syncthreads();
  if (w < 2) {
#pragma unroll
    for (int mi = 0; mi < 4; ++mi)
#pragma unroll
      for (int ni = 0; ni < 4; ++ni) acc[mi][ni] += lred[w][(mi * 4 + ni) * 64 + l];
  }
  __syncthreads();
  if (w == 1) {
#pragma unroll
    for (int mi = 0; mi < 4; ++mi)
#pragma unroll
      for (int ni = 0; ni < 4; ++ni) lred[0][(mi * 4 + ni) * 64 + l] = acc[mi][ni];
  }
  __syncthreads();
  if (w == 0) {
#pragma unroll
    for (int mi = 0; mi < 4; ++mi)
#pragma unroll
      for (int ni = 0; ni < 4; ++ni) acc[mi][ni] += lred[0][(mi * 4 + ni) * 64 + l];
    // softmax over c (rows d fixed): c values live in 4 ni-regs x 16 lanes (lr)
    const float itau = 1.f / fmaxf(expf(p_log_tau[0]), 1e-4f);
    const float beta = fminf(fmaxf(p_beta[0], 0.f), 1.f);
    const float smv = (m == 0) ? (1.f - beta) : (beta * wgt[bh * KTOP + m - 1]);
    u16* th = attT + ((size_t)m * BH + bh) * 4096;
#pragma unroll
    for (int mi = 0; mi < 4; ++mi) {
      float ev[4][4];                     // [ni][r]
#pragma unroll
      for (int r = 0; r < 4; ++r) {
        float vmax = acc[mi][0][r];
#pragma unroll
        for (int ni = 1; ni < 4; ++ni) vmax = fmaxf(vmax, acc[mi][ni][r]);
#pragma unroll
        for (int off = 8; off > 0; off >>= 1) vmax = fmaxf(vmax, __shfl_xor(vmax, off));
        float s = 0.f;
#pragma unroll
        for (int ni = 0; ni < 4; ++ni) { ev[ni][r] = expf((acc[mi][ni][r] - vmax) * itau); s += ev[ni][r]; }
#pragma unroll
        for (int off = 8; off > 0; off >>= 1) s += __shfl_xor(s, off);
        float inv = smv / s;
#pragma unroll
        for (int ni = 0; ni < 4; ++ni) ev[ni][r] *= inv;
      }
#pragma unroll
      for (int ni = 0; ni < 4; ++ni) {
        ushort4 o4 = make_ushort4(bf16r(ev[ni][0]), bf16r(ev[ni][1]), bf16r(ev[ni][2]), bf16r(ev[ni][3]));
        *(ushort4*)(th + (size_t)(16 * ni + lr) * 64 + 16 * mi + 4 * g) = o4;
      }
    }
  }
}

// ---------------- weighted contrib sum: m-split across waves + LDS reduce -----
__global__ __launch_bounds__(256) void k_contrib(const u16* __restrict__ V2,
                                                 const u16* __restrict__ attT,
                                                 const int* __restrict__ sel,
                                                 u16* __restrict__ oh) {
  const int tt = blockIdx.x;                 // 32-row t-tiles: 0..15
  const int bh = blockIdx.y;
  const int b_ = bh >> 3, h_ = bh & 7;
  const int t0 = tt * 32;
  const int tid = threadIdx.x, l = tid & 63, w = tid >> 6;
  const int lr = l & 15, lk = (l >> 4) * 8;
  __shared__ f32x4 lred[2][512];             // 16 KB
  f32x4 acc[2][4] = {};
  const u16* Vb = V2 + (size_t)bh * 65536;
  const int mstart[5] = {0, 5, 10, 15, 19};
  for (int m = mstart[w]; m < mstart[w + 1]; ++m) {
    const int lag = (m == 0) ? 0 : lag_of(sel[bh * KTOP + m - 1] & 63);
    const u16* ab = attT + ((size_t)m * BH + bh) * 4096;
#pragma unroll
    for (int ks = 0; ks < 2; ++ks) {
      const int kb2 = ks * 32 + lk;
      bf16x8 Bf[4];
#pragma unroll
      for (int ni = 0; ni < 4; ++ni) Bf[ni] = *(const bf16x8*)(ab + (size_t)(16 * ni + lr) * 64 + kb2);
#pragma unroll
      for (int mi = 0; mi < 2; ++mi) {
        const int ub = t0 + 16 * mi + 512 - lag + lr;
        bf16x8 A = *(const bf16x8*)(Vb + (size_t)ub * 64 + kb2);
#pragma unroll
        for (int ni = 0; ni < 4; ++ni)
          acc[mi][ni] = __builtin_amdgcn_mfma_f32_16x16x32_bf16(A, Bf[ni], acc[mi][ni], 0, 0, 0);
      }
    }
  }
  if (w >= 2) {
#pragma unroll
    for (int mi = 0; mi < 2; ++mi)
#pragma unroll
      for (int ni = 0; ni < 4; ++ni) lred[w - 2][(mi * 4 + ni) * 64 + l] = acc[mi][ni];
  }
  __syncthreads();
  if (w < 2) {
#pragma unroll
    for (int mi = 0; mi < 2; ++mi)
#pragma unroll
      for (int ni = 0; ni < 4; ++ni) acc[mi][ni] += lred[w][(mi * 4 + ni) * 64 + l];
  }
  __syncthreads();
  if (w == 1) {
#pragma unroll
    for (int mi = 0; mi < 2; ++mi)
#pragma unroll
      for (int ni = 0; ni < 4; ++ni) lred[0][(mi * 4 + ni) * 64 + l] = acc[mi][ni];
  }
  __syncthreads();
  if (w == 0) {
#pragma unroll
    for (int mi = 0; mi < 2; ++mi)
#pragma unroll
      for (int ni = 0; ni < 4; ++ni) {
        acc[mi][ni] += lred[0][(mi * 4 + ni) * 64 + l];
#pragma unroll
        for (int r = 0; r < 4; ++r) {
          int t = t0 + 16 * mi + (l >> 4) * 4 + r;
          int c = 16 * ni + lr;
          oh[((size_t)b_ * 512 + t) * 512 + h_ * 64 + c] = bf16r(acc[mi][ni][r]);
        }
      }
  }
}

// ---------------- final projection (MFMA, single bf16, 64-row m-tiles) --------
__global__ __launch_bounds__(256) void k_out(const u16* __restrict__ oh,
                                             const u16* __restrict__ WTh,
                                             const float* __restrict__ bo, float* __restrict__ out) {
  const u16* Bh_ = WTh + (size_t)3 * 262144;
  const int n0 = blockIdx.x * 64, m0 = blockIdx.y * 64;
  const int l = threadIdx.x & 63, w = threadIdx.x >> 6;
  const int lr = l & 15, lk = (l >> 4) * 8;
  const int arow = m0 + 16 * w + lr;
  f32x4 acc[4];
#pragma unroll
  for (int i = 0; i < 4; ++i) { float b = bo[n0 + 16 * i + lr]; acc[i] = (f32x4){b, b, b, b}; }
  for (int ks = 0; ks < 16; ++ks) {
    int kb2 = ks * 32 + lk;
    bf16x8 A = *(const bf16x8*)(oh + (size_t)arow * 512 + kb2);
#pragma unroll
    for (int i = 0; i < 4; ++i) {
      bf16x8 Bf = *(const bf16x8*)(Bh_ + (size_t)(n0 + 16 * i + lr) * 512 + kb2);
      acc[i] = __builtin_amdgcn_mfma_f32_16x16x32_bf16(A, Bf, acc[i], 0, 0, 0);
    }
  }
#pragma unroll
  for (int i = 0; i < 4; ++i)
#pragma unroll
    for (int r = 0; r < 4; ++r) {
      int m = m0 + 16 * w + (l >> 4) * 4 + r;
      int n = n0 + 16 * i + lr;
      out[(size_t)m * 512 + n] = acc[i][r];
    }
}

}  // namespace

extern "C" void kernel_launch(void* const* d_in, const int* in_sizes, int n_in,
                              void* d_out, int out_size, void* d_ws, size_t ws_size,
                              hipStream_t stream) {
  (void)in_sizes; (void)n_in; (void)out_size; (void)ws_size;
  const float* x  = (const float*)d_in[0];
  const float* Wq = (const float*)d_in[1];
  const float* bq = (const float*)d_in[2];
  const float* Wk = (const float*)d_in[3];
  const float* bk = (const float*)d_in[4];
  const float* Wv = (const float*)d_in[5];
  const float* bv = (const float*)d_in[6];
  const float* Wo = (const float*)d_in[7];
  const float* bo = (const float*)d_in[8];
  const float* p_log_tau     = (const float*)d_in[9];
  const float* p_lambda      = (const float*)d_in[10];
  const float* p_beta        = (const float*)d_in[11];
  const float* p_log_tau_lag = (const float*)d_in[12];

  char* ws = (char*)d_ws;
  const size_t MB = 1ull << 20;
  u16*   xh    = (u16*)(ws + 0 * MB);     // 2 MB
  u16*   xl    = (u16*)(ws + 2 * MB);     // 2 MB
  u16*   WTh   = (u16*)(ws + 4 * MB);     // 2 MB (q,k,v,o)
  u16*   WTl   = (u16*)(ws + 6 * MB);     // 2 MB
  u16*   QTh   = (u16*)(ws + 8 * MB);     // 2 MB  [bh][64][512]
  u16*   QTl   = (u16*)(ws + 10 * MB);    // 2 MB
  u16*   KTh   = (u16*)(ws + 12 * MB);    // 4 MB  [bh][64][1024] t-duplicated
  u16*   KTl   = (u16*)(ws + 16 * MB);    // 4 MB
  u16*   V2    = (u16*)(ws + 20 * MB);    // 4 MB  [bh][1024][64]
  float* qf    = (float*)(ws + 24 * MB);  // 4 MB (dead after k_pack)
  float* kf    = (float*)(ws + 28 * MB);  // 4 MB (dead after k_pack)
  float* vf    = (float*)(ws + 32 * MB);  // 4 MB (dead after k_pack)
  u16*   attT  = (u16*)(ws + 24 * MB);    // 4.75 MB overlay on qf/kf (after k_pack)
  u16*   oh    = (u16*)(ws + 32 * MB);    // 2 MB overlay on vf (after k_pack)
  float* score = (float*)(ws + 70 * MB);          // 8 KB
  float* wgt   = (float*)(ws + 70 * MB + 16384);  // 2.3 KB
  int*   sel   = (int*)(ws + 70 * MB + 32768);    // 2.3 KB
  float* sinv  = (float*)(ws + 70 * MB + 49152);  // 16 KB [2][32][64]

  const dim3 blk(256);

  k_prep_x<<<dim3(1024), blk, 0, stream>>>(x, xh, xl);
  k_prep_w<<<dim3(8, 8, 4), blk, 0, stream>>>(Wq, Wk, Wv, Wo, WTh, WTl);
  k_qkv<<<dim3(8, 32, 3), blk, 0, stream>>>(xh, xl, WTh, WTl, bq, bk, bv, qf, kf, vf);
  k_ssq<<<dim3(32, 2), blk, 0, stream>>>(qf, kf, sinv);
  k_pack<<<dim3(8, 32), blk, 0, stream>>>(qf, kf, vf, sinv, QTh, QTl, KTh, KTl, V2);
  k_score<<<dim3(2048), blk, 0, stream>>>(KTh, KTl, QTh, QTl, score, p_lambda);
  k_topk<<<dim3(32), dim3(64), 0, stream>>>(score, sel, wgt, p_log_tau_lag);
  k_covsm<<<dim3(608), blk, 0, stream>>>(KTh, KTl, QTh, QTl, sel, wgt, attT, p_log_tau, p_beta);
  k_contrib<<<dim3(16, 32), blk, 0, stream>>>(V2, attT, sel, oh);
  k_out<<<dim3(8, 32), blk, 0, stream>>>(oh, WTh, bo, (float*)d_out);
}

// Round 11
// 268.037 us; speedup vs baseline: 1.6498x; 1.1919x over previous
//
#include <hip/hip_runtime.h>
#include <math.h>

namespace {

typedef unsigned short u16;
typedef unsigned int   u32;
using bf16x8 = __attribute__((ext_vector_type(8))) short;
using f32x4  = __attribute__((ext_vector_type(4))) float;

constexpr int T_   = 512;
constexpr int BH   = 32;
constexpr int NLAG = 64;
constexpr int KTOP = 18;

__device__ __forceinline__ int lag_of(int li) { return (li < 63) ? (1 + 7 * li) : 511; }

__device__ __forceinline__ u16 bf16r(float f) {          // RNE fp32 -> bf16
  u32 u = __builtin_bit_cast(u32, f);
  u += 0x7fffu + ((u >> 16) & 1u);
  return (u16)(u >> 16);
}
__device__ __forceinline__ float bf2f(u16 h) {
  u32 u = ((u32)h) << 16;
  return __builtin_bit_cast(float, u);
}

// dword-aligned 16B load at even element pe, returning elements [odd .. odd+7].
__device__ __forceinline__ bf16x8 load_shift8(const u16* pe, int odd) {
  uint4 a = *(const uint4*)(pe);
  union { u32 u[4]; bf16x8 v; } r;
  if (odd) {
    u32 b = *(const u32*)(pe + 8);
    r.u[0] = __builtin_amdgcn_alignbit(a.y, a.x, 16);
    r.u[1] = __builtin_amdgcn_alignbit(a.z, a.y, 16);
    r.u[2] = __builtin_amdgcn_alignbit(a.w, a.z, 16);
    r.u[3] = __builtin_amdgcn_alignbit(b,   a.w, 16);
  } else {
    r.u[0] = a.x; r.u[1] = a.y; r.u[2] = a.z; r.u[3] = a.w;
  }
  return r.v;
}

// ---------------- x -> bf16 hi/lo split ---------------------------------------
__global__ __launch_bounds__(256) void k_prep_x(const float* __restrict__ x,
                                                u16* __restrict__ xh, u16* __restrict__ xl) {
  int i0 = (blockIdx.x * 256 + threadIdx.x) * 4;
  float4 v = *(const float4*)(x + i0);
  float vv[4] = {v.x, v.y, v.z, v.w};
  u16 h[4], lo[4];
#pragma unroll
  for (int e = 0; e < 4; ++e) { h[e] = bf16r(vv[e]); lo[e] = bf16r(vv[e] - bf2f(h[e])); }
  *(ushort4*)(xh + i0) = make_ushort4(h[0], h[1], h[2], h[3]);
  *(ushort4*)(xl + i0) = make_ushort4(lo[0], lo[1], lo[2], lo[3]);
}

// ---------------- W -> W^T bf16 hi/lo (z = q,k,v,o) ---------------------------
__global__ __launch_bounds__(256) void k_prep_w(const float* __restrict__ Wq, const float* __restrict__ Wk,
                                                const float* __restrict__ Wv, const float* __restrict__ Wo,
                                                u16* __restrict__ WTh, u16* __restrict__ WTl) {
  const int z = blockIdx.z;
  const float* W = (z == 0) ? Wq : (z == 1) ? Wk : (z == 2) ? Wv : Wo;
  u16* th = WTh + (size_t)z * 262144;
  u16* tl = WTl + (size_t)z * 262144;
  __shared__ float tile[64][65];
  const int r0 = blockIdx.y * 64, c0 = blockIdx.x * 64;
#pragma unroll
  for (int j = 0; j < 16; ++j) {
    int fid = threadIdx.x + 256 * j;
    int r = fid >> 6, c = fid & 63;
    tile[r][c] = W[(size_t)(r0 + r) * 512 + c0 + c];
  }
  __syncthreads();
#pragma unroll
  for (int j = 0; j < 16; ++j) {
    int fid = threadIdx.x + 256 * j;
    int n = fid >> 6, kk = fid & 63;
    float v = tile[kk][n];
    u16 h = bf16r(v);
    th[(size_t)(c0 + n) * 512 + r0 + kk] = h;
    tl[(size_t)(c0 + n) * 512 + r0 + kk] = bf16r(v - bf2f(h));
  }
}

// ---------------- QKV projection (MFMA, 64-row m-tiles). Q,K split ------------
__global__ __launch_bounds__(256) void k_qkv(const u16* __restrict__ xh, const u16* __restrict__ xl,
                                             const u16* __restrict__ WTh, const u16* __restrict__ WTl,
                                             const float* __restrict__ bq, const float* __restrict__ bk,
                                             const float* __restrict__ bv,
                                             float* __restrict__ qo, float* __restrict__ ko, float* __restrict__ vo) {
  const int z = blockIdx.z;
  const bool split = (z < 2);                     // Q,K feed the top-k scores: fp32-grade
  const u16* Bh_ = WTh + (size_t)z * 262144;
  const u16* Bl_ = WTl + (size_t)z * 262144;
  const float* bias = (z == 0) ? bq : (z == 1) ? bk : bv;
  float* out = (z == 0) ? qo : (z == 1) ? ko : vo;
  const int n0 = blockIdx.x * 64, m0 = blockIdx.y * 64;
  const int l = threadIdx.x & 63, w = threadIdx.x >> 6;
  const int lr = l & 15, lk = (l >> 4) * 8;
  const int arow = m0 + 16 * w + lr;
  f32x4 acc[4];
#pragma unroll
  for (int i = 0; i < 4; ++i) { float b = bias[n0 + 16 * i + lr]; acc[i] = (f32x4){b, b, b, b}; }
  for (int ks = 0; ks < 16; ++ks) {
    const int kb2 = ks * 32 + lk;
    bf16x8 A  = *(const bf16x8*)(xh + (size_t)arow * 512 + kb2);
    bf16x8 Al = {};
    if (split) Al = *(const bf16x8*)(xl + (size_t)arow * 512 + kb2);
#pragma unroll
    for (int i = 0; i < 4; ++i) {
      bf16x8 Bf = *(const bf16x8*)(Bh_ + (size_t)(n0 + 16 * i + lr) * 512 + kb2);
      acc[i] = __builtin_amdgcn_mfma_f32_16x16x32_bf16(A, Bf, acc[i], 0, 0, 0);
      if (split) {
        bf16x8 Bl2 = *(const bf16x8*)(Bl_ + (size_t)(n0 + 16 * i + lr) * 512 + kb2);
        acc[i] = __builtin_amdgcn_mfma_f32_16x16x32_bf16(A, Bl2, acc[i], 0, 0, 0);
        acc[i] = __builtin_amdgcn_mfma_f32_16x16x32_bf16(Al, Bf, acc[i], 0, 0, 0);
      }
    }
  }
#pragma unroll
  for (int i = 0; i < 4; ++i)
#pragma unroll
    for (int r = 0; r < 4; ++r) {
      int m = m0 + 16 * w + (l >> 4) * 4 + r;
      int n = n0 + 16 * i + lr;
      int b_ = m >> 9, t = m & 511, h_ = n >> 6, dh = n & 63;
      out[(((size_t)(b_ * 8 + h_)) * 512 + t) * 64 + dh] = acc[i][r];
    }
}

// ---------------- inverse L2 norms over time for Q and K ----------------------
__global__ __launch_bounds__(256) void k_ssq(const float* __restrict__ qf, const float* __restrict__ kf,
                                             float* __restrict__ sinv) {
  const int bh = blockIdx.x, which = blockIdx.y;
  const float* Xb = (which ? kf : qf) + (size_t)bh * T_ * 64;
  const int tid = threadIdx.x;
  __shared__ float red[256];
  float ss = 0.f;
  for (int i = 0; i < 128; ++i) { float v = Xb[tid + 256 * i]; ss += v * v; }
  red[tid] = ss;
  __syncthreads();
  if (tid < 64) {
    float s = red[tid] + red[tid + 64] + red[tid + 128] + red[tid + 192];
    sinv[which * 2048 + bh * 64 + tid] = 1.0f / sqrtf(fmaxf(s, 1e-8f));
  }
}

// ---------------- pack: Q fragment-linear hi/lo, K^T dup hi/lo, V dup ---------
// QP layout: [bh][ni(4)][tc(16)][lane(64)][8]  with value
//   QP[bh][ni][tc][16g+lr][j] = Qhat[t = 32*tc + 8g + j][c = 16*ni + lr]
// so an MFMA B-frag load is 64 lanes x 16B contiguous (1KB, fully coalesced).
__global__ __launch_bounds__(256) void k_pack(const float* __restrict__ qf, const float* __restrict__ kf,
                                              const float* __restrict__ vf, const float* __restrict__ sinv,
                                              u16* __restrict__ QPh, u16* __restrict__ QPl,
                                              u16* __restrict__ KTh, u16* __restrict__ KTl,
                                              u16* __restrict__ V2) {
  const int t0 = blockIdx.x * 64, bh = blockIdx.y;
  const int tid = threadIdx.x;
  const int tc0 = blockIdx.x * 2;
  __shared__ float tile[64][65];
  // ---- Q: normalize into tile ----
#pragma unroll
  for (int j = 0; j < 16; ++j) {
    int fid = tid + 256 * j;
    int r = fid >> 6, c = fid & 63;
    tile[r][c] = qf[((size_t)bh * 512 + t0 + r) * 64 + c] * sinv[bh * 64 + c];
  }
  __syncthreads();
  // ---- Q: write fragment-linear slabs (8 slabs: ni x tcl) ----
  {
    const int l = tid >> 2, jp = (tid & 3) * 2;
    const int g = l >> 4, lr = l & 15;
#pragma unroll
    for (int s = 0; s < 8; ++s) {
      int ni = s >> 1, tcl = s & 1;
      float v0 = tile[32 * tcl + 8 * g + jp][16 * ni + lr];
      float v1 = tile[32 * tcl + 8 * g + jp + 1][16 * ni + lr];
      u16 h0 = bf16r(v0), h1 = bf16r(v1);
      u16 l0 = bf16r(v0 - bf2f(h0)), l1 = bf16r(v1 - bf2f(h1));
      size_t off = (size_t)bh * 32768 + (size_t)(ni * 16 + tc0 + tcl) * 512 + l * 8 + jp;
      *(ushort2*)(QPh + off) = make_ushort2(h0, h1);
      *(ushort2*)(QPl + off) = make_ushort2(l0, l1);
    }
  }
  __syncthreads();
  // ---- K: normalize, transpose, duplicate in t, hi/lo ----
#pragma unroll
  for (int j = 0; j < 16; ++j) {
    int fid = tid + 256 * j;
    int r = fid >> 6, c = fid & 63;
    tile[r][c] = kf[((size_t)bh * 512 + t0 + r) * 64 + c] * sinv[2048 + bh * 64 + c];
  }
  __syncthreads();
#pragma unroll
  for (int j = 0; j < 16; ++j) {
    int fid = tid + 256 * j;
    int c = fid >> 6, tl2 = fid & 63;
    float v = tile[tl2][c];
    u16 hh = bf16r(v);
    u16 ll = bf16r(v - bf2f(hh));
    size_t base = ((size_t)bh * 64 + c) * 1024 + t0 + tl2;
    KTh[base] = hh;       KTl[base] = ll;
    KTh[base + 512] = hh; KTl[base + 512] = ll;
  }
  // ---- V: duplicate rows, single bf16, natural layout ----
#pragma unroll
  for (int j = 0; j < 4; ++j) {
    int r = (tid >> 4) + 16 * j, c4 = (tid & 15) * 4;
    float4 v4 = *(const float4*)(vf + ((size_t)bh * 512 + t0 + r) * 64 + c4);
    ushort4 o = make_ushort4(bf16r(v4.x), bf16r(v4.y), bf16r(v4.z), bf16r(v4.w));
    size_t base = ((size_t)bh * 1024 + t0 + r) * 64 + c4;
    *(ushort4*)(V2 + base) = o;
    *(ushort4*)(V2 + base + 512 * 64) = o;
  }
}

// ---------------- cov (65 lags) + scores; coalesced B, XCD-bh-affine ----------
// grid 2080: xcd = wg&7 owns bh in [xcd*4, xcd*4+4); 65 lags per bh.
// 4-way K-split, acc[4][4]/wave, 32KB LDS reduce, launch_bounds(256,2): no spill.
__global__ __launch_bounds__(256, 2) void k_cov(const u16* __restrict__ KTh, const u16* __restrict__ KTl,
                                                const u16* __restrict__ QPh, const u16* __restrict__ QPl,
                                                float* __restrict__ cov, float* __restrict__ score,
                                                const float* __restrict__ p_lambda) {
  const int wg = blockIdx.x;
  const int xcd = wg & 7, jj = wg >> 3;           // jj: 0..259
  const int bh = xcd * 4 + jj / 65;
  const int li = jj % 65;                         // 0 => lag0; 1..64 => candidates
  const int lag = (li == 0) ? 0 : lag_of(li - 1);
  const int tid = threadIdx.x, l = tid & 63, w = tid >> 6;
  const int lr = l & 15, lk = (l >> 4) * 8;
  __shared__ f32x4 lred[2][1024];                 // 32 KB
  const int shift = 512 - lag;
  const int sbase = shift & ~1;
  const int odd = shift & 1;
  const u16* qp_h = QPh + (size_t)bh * 32768 + (size_t)l * 8;
  const u16* qp_l = QPl + (size_t)bh * 32768 + (size_t)l * 8;
  const u16* kh = KTh + (size_t)bh * 65536 + (size_t)lr * 1024 + w * 128 + lk + sbase;
  const u16* kl = KTl + (size_t)bh * 65536 + (size_t)lr * 1024 + w * 128 + lk + sbase;
  f32x4 acc[4][4] = {};
#pragma unroll
  for (int kk = 0; kk < 4; ++kk) {
    const int o = kk * 32;
    const int tc = w * 4 + kk;
    bf16x8 Bh2[4], Bl2[4];
#pragma unroll
    for (int ni = 0; ni < 4; ++ni) {
      size_t soff = (size_t)(ni * 16 + tc) * 512;
      Bh2[ni] = *(const bf16x8*)(qp_h + soff);
      Bl2[ni] = *(const bf16x8*)(qp_l + soff);
    }
#pragma unroll
    for (int mi = 0; mi < 4; ++mi) {
      bf16x8 Ah = load_shift8(kh + mi * 16384 + o, odd);
      bf16x8 Al = load_shift8(kl + mi * 16384 + o, odd);
#pragma unroll
      for (int ni = 0; ni < 4; ++ni) {
        acc[mi][ni] = __builtin_amdgcn_mfma_f32_16x16x32_bf16(Ah, Bh2[ni], acc[mi][ni], 0, 0, 0);
        acc[mi][ni] = __builtin_amdgcn_mfma_f32_16x16x32_bf16(Ah, Bl2[ni], acc[mi][ni], 0, 0, 0);
        acc[mi][ni] = __builtin_amdgcn_mfma_f32_16x16x32_bf16(Al, Bh2[ni], acc[mi][ni], 0, 0, 0);
      }
    }
  }
  if (w >= 2) {
#pragma unroll
    for (int mi = 0; mi < 4; ++mi)
#pragma unroll
      for (int ni = 0; ni < 4; ++ni) lred[w - 2][(mi * 4 + ni) * 64 + l] = acc[mi][ni];
  }
  __syncthreads();
  if (w < 2) {
#pragma unroll
    for (int mi = 0; mi < 4; ++mi)
#pragma unroll
      for (int ni = 0; ni < 4; ++ni) acc[mi][ni] += lred[w][(mi * 4 + ni) * 64 + l];
  }
  __syncthreads();
  if (w == 1) {
#pragma unroll
    for (int mi = 0; mi < 4; ++mi)
#pragma unroll
      for (int ni = 0; ni < 4; ++ni) lred[0][(mi * 4 + ni) * 64 + l] = acc[mi][ni];
  }
  __syncthreads();
  if (w == 0) {
    float* cb = cov + ((size_t)li * BH + bh) * 4096;
    float labs = 0.f, ldiag = 0.f;
#pragma unroll
    for (int mi = 0; mi < 4; ++mi)
#pragma unroll
      for (int ni = 0; ni < 4; ++ni) {
        acc[mi][ni] += lred[0][(mi * 4 + ni) * 64 + l];
#pragma unroll
        for (int r = 0; r < 4; ++r) {
          int d = 16 * mi + (l >> 4) * 4 + r;
          int c = 16 * ni + lr;
          float vv = acc[mi][ni][r];
          cb[(size_t)d * 64 + c] = vv;
          labs += fabsf(vv);
          if (d == c) ldiag += fabsf(vv);
        }
      }
#pragma unroll
    for (int off = 32; off > 0; off >>= 1) {
      labs += __shfl_xor(labs, off);
      ldiag += __shfl_xor(ldiag, off);
    }
    if (l == 0 && li > 0) {
      float lam = fminf(fmaxf(p_lambda[0], 0.f), 1.f);
      score[(size_t)bh * NLAG + (li - 1)] = lam * ldiag + (1.f - lam) * (labs - ldiag);
    }
  }
}

// ---------------- top-18: one wave per bh, register-resident argmax -----------
__global__ void k_topk(const float* __restrict__ score, int* __restrict__ sel,
                       float* __restrict__ wgt, const float* __restrict__ p_log_tau_lag) {
  const int bh = blockIdx.x;
  const int lane = threadIdx.x;        // 64 lanes = 1 wave
  float sc = score[(size_t)bh * NLAG + lane];
  float ts[KTOP];
  int ti[KTOP];
#pragma unroll
  for (int k = 0; k < KTOP; ++k) {
    float v = sc;
    int idx = lane;
#pragma unroll
    for (int off = 32; off > 0; off >>= 1) {
      float ov = __shfl_xor(v, off);
      int oi = __shfl_xor(idx, off);
      if (ov > v || (ov == v && oi < idx)) { v = ov; idx = oi; }
    }
    ts[k] = v;
    ti[k] = idx;
    if (lane == idx) sc = -3e38f;      // remove winner (tie -> lowest index, like lax.top_k)
  }
  const float tau_lag = fmaxf(expf(p_log_tau_lag[0]), 1e-4f);
  const float mx = ts[0];
  float e[KTOP];
  float sum = 0.f;
#pragma unroll
  for (int k = 0; k < KTOP; ++k) { e[k] = expf((ts[k] - mx) / tau_lag); sum += e[k]; }
  const float rs = 1.0f / sum;
  if (lane < KTOP) {
    sel[bh * KTOP + lane] = ti[lane];
    wgt[bh * KTOP + lane] = e[lane] * rs;
  }
}

// ---------------- softmax of 19 selected cov; writes attP fragment-linear -----
// attP layout per (m,bh): [ni(4)][tc(2)][lane(64)][8]:
//   attP[..][ni][tc][16g+lr][j] = att[d = 32*tc + 8g + j][c = 16*ni + lr] * smv
__global__ __launch_bounds__(256) void k_attsm(const float* __restrict__ cov, const int* __restrict__ sel,
                                               const float* __restrict__ wgt,
                                               u16* __restrict__ attP,
                                               const float* __restrict__ p_log_tau,
                                               const float* __restrict__ p_beta) {
  const int bh = blockIdx.x, m = blockIdx.y;
  const int slot = (m == 0) ? 0 : (1 + (sel[bh * KTOP + m - 1] & 63));
  const float beta = fminf(fmaxf(p_beta[0], 0.f), 1.f);
  const float smv = (m == 0) ? (1.f - beta) : (beta * wgt[bh * KTOP + m - 1]);
  const float itau = 1.f / fmaxf(expf(p_log_tau[0]), 1e-4f);
  const float* cb = cov + ((size_t)slot * BH + bh) * 4096;
  __shared__ float att_s[64][66];
  const int lane = threadIdx.x & 63, wv = threadIdx.x >> 6;
  for (int d = wv; d < 64; d += 4) {
    float v = cb[(size_t)d * 64 + lane] * itau;
    float mx = v;
#pragma unroll
    for (int off = 32; off > 0; off >>= 1) mx = fmaxf(mx, __shfl_xor(mx, off));
    float e = expf(v - mx);
    float sm2 = e;
#pragma unroll
    for (int off = 32; off > 0; off >>= 1) sm2 += __shfl_xor(sm2, off);
    att_s[d][lane] = (e / sm2) * smv;
  }
  __syncthreads();
  u16* th = attP + ((size_t)m * BH + bh) * 4096;
  const int l = threadIdx.x >> 2, jp = (threadIdx.x & 3) * 2;
  const int g = l >> 4, lr = l & 15;
#pragma unroll
  for (int s = 0; s < 8; ++s) {
    int ni = s >> 1, tc = s & 1;
    float v0 = att_s[32 * tc + 8 * g + jp][16 * ni + lr];
    float v1 = att_s[32 * tc + 8 * g + jp + 1][16 * ni + lr];
    *(ushort2*)(th + (size_t)(ni * 2 + tc) * 512 + l * 8 + jp) = make_ushort2(bf16r(v0), bf16r(v1));
  }
}

// ---------------- weighted contrib sum: m-split across waves + LDS reduce -----
__global__ __launch_bounds__(256) void k_contrib(const u16* __restrict__ V2,
                                                 const u16* __restrict__ attP,
                                                 const int* __restrict__ sel,
                                                 u16* __restrict__ oh) {
  const int tt = blockIdx.x;                 // 32-row t-tiles: 0..15
  const int bh = blockIdx.y;
  const int b_ = bh >> 3, h_ = bh & 7;
  const int t0 = tt * 32;
  const int tid = threadIdx.x, l = tid & 63, w = tid >> 6;
  const int lr = l & 15, lk = (l >> 4) * 8;
  __shared__ f32x4 lred[2][512];             // 16 KB
  f32x4 acc[2][4] = {};
  const u16* Vb = V2 + (size_t)bh * 65536;
  const int mstart[5] = {0, 5, 10, 15, 19};
  for (int m = mstart[w]; m < mstart[w + 1]; ++m) {
    const int lag = (m == 0) ? 0 : lag_of(sel[bh * KTOP + m - 1] & 63);
    const u16* ab = attP + ((size_t)m * BH + bh) * 4096;
#pragma unroll
    for (int ks = 0; ks < 2; ++ks) {
      const int kb2 = ks * 32 + lk;
      bf16x8 Bf[4];
#pragma unroll
      for (int ni = 0; ni < 4; ++ni)
        Bf[ni] = *(const bf16x8*)(ab + (size_t)(ni * 2 + ks) * 512 + l * 8);
#pragma unroll
      for (int mi = 0; mi < 2; ++mi) {
        const int ub = t0 + 16 * mi + 512 - lag + lr;
        bf16x8 A = *(const bf16x8*)(Vb + (size_t)ub * 64 + kb2);
#pragma unroll
        for (int ni = 0; ni < 4; ++ni)
          acc[mi][ni] = __builtin_amdgcn_mfma_f32_16x16x32_bf16(A, Bf[ni], acc[mi][ni], 0, 0, 0);
      }
    }
  }
  if (w >= 2) {
#pragma unroll
    for (int mi = 0; mi < 2; ++mi)
#pragma unroll
      for (int ni = 0; ni < 4; ++ni) lred[w - 2][(mi * 4 + ni) * 64 + l] = acc[mi][ni];
  }
  __syncthreads();
  if (w < 2) {
#pragma unroll
    for (int mi = 0; mi < 2; ++mi)
#pragma unroll
      for (int ni = 0; ni < 4; ++ni) acc[mi][ni] += lred[w][(mi * 4 + ni) * 64 + l];
  }
  __syncthreads();
  if (w == 1) {
#pragma unroll
    for (int mi = 0; mi < 2; ++mi)
#pragma unroll
      for (int ni = 0; ni < 4; ++ni) lred[0][(mi * 4 + ni) * 64 + l] = acc[mi][ni];
  }
  __syncthreads();
  if (w == 0) {
#pragma unroll
    for (int mi = 0; mi < 2; ++mi)
#pragma unroll
      for (int ni = 0; ni < 4; ++ni) {
        acc[mi][ni] += lred[0][(mi * 4 + ni) * 64 + l];
#pragma unroll
        for (int r = 0; r < 4; ++r) {
          int t = t0 + 16 * mi + (l >> 4) * 4 + r;
          int c = 16 * ni + lr;
          oh[((size_t)b_ * 512 + t) * 512 + h_ * 64 + c] = bf16r(acc[mi][ni][r]);
        }
      }
  }
}

// ---------------- final projection (MFMA, single bf16, 64-row m-tiles) --------
__global__ __launch_bounds__(256) void k_out(const u16* __restrict__ oh,
                                             const u16* __restrict__ WTh,
                                             const float* __restrict__ bo, float* __restrict__ out) {
  const u16* Bh_ = WTh + (size_t)3 * 262144;
  const int n0 = blockIdx.x * 64, m0 = blockIdx.y * 64;
  const int l = threadIdx.x & 63, w = threadIdx.x >> 6;
  const int lr = l & 15, lk = (l >> 4) * 8;
  const int arow = m0 + 16 * w + lr;
  f32x4 acc[4];
#pragma unroll
  for (int i = 0; i < 4; ++i) { float b = bo[n0 + 16 * i + lr]; acc[i] = (f32x4){b, b, b, b}; }
  for (int ks = 0; ks < 16; ++ks) {
    int kb2 = ks * 32 + lk;
    bf16x8 A = *(const bf16x8*)(oh + (size_t)arow * 512 + kb2);
#pragma unroll
    for (int i = 0; i < 4; ++i) {
      bf16x8 Bf = *(const bf16x8*)(Bh_ + (size_t)(n0 + 16 * i + lr) * 512 + kb2);
      acc[i] = __builtin_amdgcn_mfma_f32_16x16x32_bf16(A, Bf, acc[i], 0, 0, 0);
    }
  }
#pragma unroll
  for (int i = 0; i < 4; ++i)
#pragma unroll
    for (int r = 0; r < 4; ++r) {
      int m = m0 + 16 * w + (l >> 4) * 4 + r;
      int n = n0 + 16 * i + lr;
      out[(size_t)m * 512 + n] = acc[i][r];
    }
}

}  // namespace

extern "C" void kernel_launch(void* const* d_in, const int* in_sizes, int n_in,
                              void* d_out, int out_size, void* d_ws, size_t ws_size,
                              hipStream_t stream) {
  (void)in_sizes; (void)n_in; (void)out_size; (void)ws_size;
  const float* x  = (const float*)d_in[0];
  const float* Wq = (const float*)d_in[1];
  const float* bq = (const float*)d_in[2];
  const float* Wk = (const float*)d_in[3];
  const float* bk = (const float*)d_in[4];
  const float* Wv = (const float*)d_in[5];
  const float* bv = (const float*)d_in[6];
  const float* Wo = (const float*)d_in[7];
  const float* bo = (const float*)d_in[8];
  const float* p_log_tau     = (const float*)d_in[9];
  const float* p_lambda      = (const float*)d_in[10];
  const float* p_beta        = (const float*)d_in[11];
  const float* p_log_tau_lag = (const float*)d_in[12];

  char* ws = (char*)d_ws;
  const size_t MB = 1ull << 20;
  u16*   xh    = (u16*)(ws + 0 * MB);     // 2 MB
  u16*   xl    = (u16*)(ws + 2 * MB);     // 2 MB
  u16*   WTh   = (u16*)(ws + 4 * MB);     // 2 MB (q,k,v,o)
  u16*   WTl   = (u16*)(ws + 6 * MB);     // 2 MB
  u16*   QPh   = (u16*)(ws + 8 * MB);     // 2 MB  fragment-linear Q
  u16*   QPl   = (u16*)(ws + 10 * MB);    // 2 MB
  u16*   KTh   = (u16*)(ws + 12 * MB);    // 4 MB  [bh][64][1024] t-duplicated
  u16*   KTl   = (u16*)(ws + 16 * MB);    // 4 MB
  u16*   V2    = (u16*)(ws + 20 * MB);    // 4 MB  [bh][1024][64]
  float* qf    = (float*)(ws + 24 * MB);  // 4 MB (dead after k_pack)
  float* kf    = (float*)(ws + 28 * MB);  // 4 MB (dead after k_pack)
  float* vf    = (float*)(ws + 32 * MB);  // 4 MB (dead after k_pack)
  u16*   attP  = (u16*)(ws + 24 * MB);    // 4.75 MB overlay on qf/kf (after k_pack)
  u16*   oh    = (u16*)(ws + 32 * MB);    // 2 MB overlay on vf (after k_pack)
  float* cov   = (float*)(ws + 36 * MB);  // 34 MB (65*32*4096 fp32)
  float* score = (float*)(ws + 70 * MB);          // 8 KB
  float* wgt   = (float*)(ws + 70 * MB + 16384);  // 2.3 KB
  int*   sel   = (int*)(ws + 70 * MB + 32768);    // 2.3 KB
  float* sinv  = (float*)(ws + 70 * MB + 49152);  // 16 KB [2][32][64]

  const dim3 blk(256);

  k_prep_x<<<dim3(1024), blk, 0, stream>>>(x, xh, xl);
  k_prep_w<<<dim3(8, 8, 4), blk, 0, stream>>>(Wq, Wk, Wv, Wo, WTh, WTl);
  k_qkv<<<dim3(8, 32, 3), blk, 0, stream>>>(xh, xl, WTh, WTl, bq, bk, bv, qf, kf, vf);
  k_ssq<<<dim3(32, 2), blk, 0, stream>>>(qf, kf, sinv);
  k_pack<<<dim3(8, 32), blk, 0, stream>>>(qf, kf, vf, sinv, QPh, QPl, KTh, KTl, V2);
  k_cov<<<dim3(2080), blk, 0, stream>>>(KTh, KTl, QPh, QPl, cov, score, p_lambda);
  k_topk<<<dim3(32), dim3(64), 0, stream>>>(score, sel, wgt, p_log_tau_lag);
  k_attsm<<<dim3(32, 19), blk, 0, stream>>>(cov, sel, wgt, attP, p_log_tau, p_beta);
  k_contrib<<<dim3(16, 32), blk, 0, stream>>>(V2, attP, sel, oh);
  k_out<<<dim3(8, 32), blk, 0, stream>>>(oh, WTh, bo, (float*)d_out);
}

// Round 12
// 234.369 us; speedup vs baseline: 1.8868x; 1.1437x over previous
//
#include <hip/hip_runtime.h>
#include <math.h>

namespace {

typedef unsigned short u16;
typedef unsigned int   u32;
using bf16x8 = __attribute__((ext_vector_type(8))) short;
using f32x4  = __attribute__((ext_vector_type(4))) float;

constexpr int T_   = 512;
constexpr int BH   = 32;
constexpr int NLAG = 64;
constexpr int KTOP = 18;

__device__ __forceinline__ int lag_of(int li) { return (li < 63) ? (1 + 7 * li) : 511; }

__device__ __forceinline__ u16 bf16r(float f) {          // RNE fp32 -> bf16
  u32 u = __builtin_bit_cast(u32, f);
  u += 0x7fffu + ((u >> 16) & 1u);
  return (u16)(u >> 16);
}
__device__ __forceinline__ float bf2f(u16 h) {
  u32 u = ((u32)h) << 16;
  return __builtin_bit_cast(float, u);
}

// ---------------- x -> bf16 hi/lo split ---------------------------------------
__global__ __launch_bounds__(256) void k_prep_x(const float* __restrict__ x,
                                                u16* __restrict__ xh, u16* __restrict__ xl) {
  int i0 = (blockIdx.x * 256 + threadIdx.x) * 4;
  float4 v = *(const float4*)(x + i0);
  float vv[4] = {v.x, v.y, v.z, v.w};
  u16 h[4], lo[4];
#pragma unroll
  for (int e = 0; e < 4; ++e) { h[e] = bf16r(vv[e]); lo[e] = bf16r(vv[e] - bf2f(h[e])); }
  *(ushort4*)(xh + i0) = make_ushort4(h[0], h[1], h[2], h[3]);
  *(ushort4*)(xl + i0) = make_ushort4(lo[0], lo[1], lo[2], lo[3]);
}

// ---------------- W -> W^T bf16 hi/lo (z = q,k,v,o) ---------------------------
__global__ __launch_bounds__(256) void k_prep_w(const float* __restrict__ Wq, const float* __restrict__ Wk,
                                                const float* __restrict__ Wv, const float* __restrict__ Wo,
                                                u16* __restrict__ WTh, u16* __restrict__ WTl) {
  const int z = blockIdx.z;
  const float* W = (z == 0) ? Wq : (z == 1) ? Wk : (z == 2) ? Wv : Wo;
  u16* th = WTh + (size_t)z * 262144;
  u16* tl = WTl + (size_t)z * 262144;
  __shared__ float tile[64][65];
  const int r0 = blockIdx.y * 64, c0 = blockIdx.x * 64;
#pragma unroll
  for (int j = 0; j < 16; ++j) {
    int fid = threadIdx.x + 256 * j;
    int r = fid >> 6, c = fid & 63;
    tile[r][c] = W[(size_t)(r0 + r) * 512 + c0 + c];
  }
  __syncthreads();
#pragma unroll
  for (int j = 0; j < 16; ++j) {
    int fid = threadIdx.x + 256 * j;
    int n = fid >> 6, kk = fid & 63;
    float v = tile[kk][n];
    u16 h = bf16r(v);
    th[(size_t)(c0 + n) * 512 + r0 + kk] = h;
    tl[(size_t)(c0 + n) * 512 + r0 + kk] = bf16r(v - bf2f(h));
  }
}

// ---------------- QKV projection (MFMA, 64-row m-tiles). Q,K split ------------
__global__ __launch_bounds__(256) void k_qkv(const u16* __restrict__ xh, const u16* __restrict__ xl,
                                             const u16* __restrict__ WTh, const u16* __restrict__ WTl,
                                             const float* __restrict__ bq, const float* __restrict__ bk,
                                             const float* __restrict__ bv,
                                             float* __restrict__ qo, float* __restrict__ ko, float* __restrict__ vo) {
  const int z = blockIdx.z;
  const bool split = (z < 2);                     // Q,K feed the top-k scores: fp32-grade
  const u16* Bh_ = WTh + (size_t)z * 262144;
  const u16* Bl_ = WTl + (size_t)z * 262144;
  const float* bias = (z == 0) ? bq : (z == 1) ? bk : bv;
  float* out = (z == 0) ? qo : (z == 1) ? ko : vo;
  const int n0 = blockIdx.x * 64, m0 = blockIdx.y * 64;
  const int l = threadIdx.x & 63, w = threadIdx.x >> 6;
  const int lr = l & 15, lk = (l >> 4) * 8;
  const int arow = m0 + 16 * w + lr;
  f32x4 acc[4];
#pragma unroll
  for (int i = 0; i < 4; ++i) { float b = bias[n0 + 16 * i + lr]; acc[i] = (f32x4){b, b, b, b}; }
  for (int ks = 0; ks < 16; ++ks) {
    const int kb2 = ks * 32 + lk;
    bf16x8 A  = *(const bf16x8*)(xh + (size_t)arow * 512 + kb2);
    bf16x8 Al = {};
    if (split) Al = *(const bf16x8*)(xl + (size_t)arow * 512 + kb2);
#pragma unroll
    for (int i = 0; i < 4; ++i) {
      bf16x8 Bf = *(const bf16x8*)(Bh_ + (size_t)(n0 + 16 * i + lr) * 512 + kb2);
      acc[i] = __builtin_amdgcn_mfma_f32_16x16x32_bf16(A, Bf, acc[i], 0, 0, 0);
      if (split) {
        bf16x8 Bl2 = *(const bf16x8*)(Bl_ + (size_t)(n0 + 16 * i + lr) * 512 + kb2);
        acc[i] = __builtin_amdgcn_mfma_f32_16x16x32_bf16(A, Bl2, acc[i], 0, 0, 0);
        acc[i] = __builtin_amdgcn_mfma_f32_16x16x32_bf16(Al, Bf, acc[i], 0, 0, 0);
      }
    }
  }
#pragma unroll
  for (int i = 0; i < 4; ++i)
#pragma unroll
    for (int r = 0; r < 4; ++r) {
      int m = m0 + 16 * w + (l >> 4) * 4 + r;
      int n = n0 + 16 * i + lr;
      int b_ = m >> 9, t = m & 511, h_ = n >> 6, dh = n & 63;
      out[(((size_t)(b_ * 8 + h_)) * 512 + t) * 64 + dh] = acc[i][r];
    }
}

// ---------------- inverse L2 norms over time for Q and K ----------------------
__global__ __launch_bounds__(256) void k_ssq(const float* __restrict__ qf, const float* __restrict__ kf,
                                             float* __restrict__ sinv) {
  const int bh = blockIdx.x, which = blockIdx.y;
  const float* Xb = (which ? kf : qf) + (size_t)bh * T_ * 64;
  const int tid = threadIdx.x;
  __shared__ float red[256];
  float ss = 0.f;
  for (int i = 0; i < 128; ++i) { float v = Xb[tid + 256 * i]; ss += v * v; }
  red[tid] = ss;
  __syncthreads();
  if (tid < 64) {
    float s = red[tid] + red[tid + 64] + red[tid + 128] + red[tid + 192];
    sinv[which * 2048 + bh * 64 + tid] = 1.0f / sqrtf(fmaxf(s, 1e-8f));
  }
}

// ---------------- pack: Q fragment-linear hi/lo, K^T dup interleaved, V dup ---
// QP layout: [bh][ni(4)][tc(16)][lane(64)][8]
// KT2 layout: [bh][d(64)][t(1024, duplicated)][2] = {hi, lo} interleaved
__global__ __launch_bounds__(256) void k_pack(const float* __restrict__ qf, const float* __restrict__ kf,
                                              const float* __restrict__ vf, const float* __restrict__ sinv,
                                              u16* __restrict__ QPh, u16* __restrict__ QPl,
                                              u16* __restrict__ KT2,
                                              u16* __restrict__ V2) {
  const int t0 = blockIdx.x * 64, bh = blockIdx.y;
  const int tid = threadIdx.x;
  const int tc0 = blockIdx.x * 2;
  __shared__ float tile[64][65];
  // ---- Q: normalize into tile ----
#pragma unroll
  for (int j = 0; j < 16; ++j) {
    int fid = tid + 256 * j;
    int r = fid >> 6, c = fid & 63;
    tile[r][c] = qf[((size_t)bh * 512 + t0 + r) * 64 + c] * sinv[bh * 64 + c];
  }
  __syncthreads();
  // ---- Q: write fragment-linear slabs (8 slabs: ni x tcl) ----
  {
    const int l = tid >> 2, jp = (tid & 3) * 2;
    const int g = l >> 4, lr = l & 15;
#pragma unroll
    for (int s = 0; s < 8; ++s) {
      int ni = s >> 1, tcl = s & 1;
      float v0 = tile[32 * tcl + 8 * g + jp][16 * ni + lr];
      float v1 = tile[32 * tcl + 8 * g + jp + 1][16 * ni + lr];
      u16 h0 = bf16r(v0), h1 = bf16r(v1);
      u16 l0 = bf16r(v0 - bf2f(h0)), l1 = bf16r(v1 - bf2f(h1));
      size_t off = (size_t)bh * 32768 + (size_t)(ni * 16 + tc0 + tcl) * 512 + l * 8 + jp;
      *(ushort2*)(QPh + off) = make_ushort2(h0, h1);
      *(ushort2*)(QPl + off) = make_ushort2(l0, l1);
    }
  }
  __syncthreads();
  // ---- K: normalize, transpose, duplicate in t, hi/lo interleaved ----
#pragma unroll
  for (int j = 0; j < 16; ++j) {
    int fid = tid + 256 * j;
    int r = fid >> 6, c = fid & 63;
    tile[r][c] = kf[((size_t)bh * 512 + t0 + r) * 64 + c] * sinv[2048 + bh * 64 + c];
  }
  __syncthreads();
#pragma unroll
  for (int j = 0; j < 16; ++j) {
    int fid = tid + 256 * j;
    int c = fid >> 6, tl2 = fid & 63;
    float v = tile[tl2][c];
    u16 hh = bf16r(v);
    u16 ll = bf16r(v - bf2f(hh));
    size_t base = ((size_t)bh * 64 + c) * 1024 + t0 + tl2;
    *(ushort2*)(KT2 + 2 * base) = make_ushort2(hh, ll);
    *(ushort2*)(KT2 + 2 * (base + 512)) = make_ushort2(hh, ll);
  }
  // ---- V: duplicate rows, single bf16, natural layout ----
#pragma unroll
  for (int j = 0; j < 4; ++j) {
    int r = (tid >> 4) + 16 * j, c4 = (tid & 15) * 4;
    float4 v4 = *(const float4*)(vf + ((size_t)bh * 512 + t0 + r) * 64 + c4);
    ushort4 o = make_ushort4(bf16r(v4.x), bf16r(v4.y), bf16r(v4.z), bf16r(v4.w));
    size_t base = ((size_t)bh * 1024 + t0 + r) * 64 + c4;
    *(ushort4*)(V2 + base) = o;
    *(ushort4*)(V2 + base + 512 * 64) = o;
  }
}

// ---------------- cov (65 lags) + scores; both operands line-efficient --------
// grid 2080: xcd = wg&7 owns bh in [xcd*4, xcd*4+4); 65 lags per bh.
// A-side: KT2 interleaved -> 32B/lane contiguous, hi+lo share 128B lines.
// cov stored FRAGMENT-LINEAR: cov[(li*32+bh)*4096 + (mi*4+ni)*256 + l*4 + r].
__global__ __launch_bounds__(256, 2) void k_cov(const u16* __restrict__ KT2,
                                                const u16* __restrict__ QPh, const u16* __restrict__ QPl,
                                                float* __restrict__ cov, float* __restrict__ score,
                                                const float* __restrict__ p_lambda) {
  const int wg = blockIdx.x;
  const int xcd = wg & 7, jj = wg >> 3;           // jj: 0..259
  const int bh = xcd * 4 + jj / 65;
  const int li = jj % 65;                         // 0 => lag0; 1..64 => candidates
  const int lag = (li == 0) ? 0 : lag_of(li - 1);
  const int tid = threadIdx.x, l = tid & 63, w = tid >> 6;
  const int lr = l & 15, lk = (l >> 4) * 8;
  __shared__ f32x4 lred[2][1024];                 // 32 KB
  const int shift = 512 - lag;                    // 1..512
  const u16* qp_h = QPh + (size_t)bh * 32768 + (size_t)l * 8;
  const u16* qp_l = QPl + (size_t)bh * 32768 + (size_t)l * 8;
  // element index of this lane's frag start in KT2 row (d = lr [+16mi]):
  const u16* k2 = KT2 + 2 * (((size_t)bh * 64 + lr) * 1024 + (size_t)(shift + w * 128 + lk));
  f32x4 acc[4][4] = {};
#pragma unroll
  for (int kk = 0; kk < 4; ++kk) {
    const int o = kk * 32;
    const int tc = w * 4 + kk;
    bf16x8 Bh2[4], Bl2[4];
#pragma unroll
    for (int ni = 0; ni < 4; ++ni) {
      size_t soff = (size_t)(ni * 16 + tc) * 512;
      Bh2[ni] = *(const bf16x8*)(qp_h + soff);
      Bl2[ni] = *(const bf16x8*)(qp_l + soff);
    }
#pragma unroll
    for (int mi = 0; mi < 4; ++mi) {
      const u16* pa = k2 + (size_t)mi * 32768 + 2 * o;   // row d=16mi+lr, elems interleaved
      uint4 a = *(const uint4*)(pa);
      uint4 b = *(const uint4*)(pa + 8);
      union { u32 u[4]; bf16x8 v; } Ah, Al;
      Ah.u[0] = __builtin_amdgcn_perm(a.y, a.x, 0x05040100u);
      Al.u[0] = __builtin_amdgcn_perm(a.y, a.x, 0x07060302u);
      Ah.u[1] = __builtin_amdgcn_perm(a.w, a.z, 0x05040100u);
      Al.u[1] = __builtin_amdgcn_perm(a.w, a.z, 0x07060302u);
      Ah.u[2] = __builtin_amdgcn_perm(b.y, b.x, 0x05040100u);
      Al.u[2] = __builtin_amdgcn_perm(b.y, b.x, 0x07060302u);
      Ah.u[3] = __builtin_amdgcn_perm(b.w, b.z, 0x05040100u);
      Al.u[3] = __builtin_amdgcn_perm(b.w, b.z, 0x07060302u);
#pragma unroll
      for (int ni = 0; ni < 4; ++ni) {
        acc[mi][ni] = __builtin_amdgcn_mfma_f32_16x16x32_bf16(Ah.v, Bh2[ni], acc[mi][ni], 0, 0, 0);
        acc[mi][ni] = __builtin_amdgcn_mfma_f32_16x16x32_bf16(Ah.v, Bl2[ni], acc[mi][ni], 0, 0, 0);
        acc[mi][ni] = __builtin_amdgcn_mfma_f32_16x16x32_bf16(Al.v, Bh2[ni], acc[mi][ni], 0, 0, 0);
      }
    }
  }
  if (w >= 2) {
#pragma unroll
    for (int mi = 0; mi < 4; ++mi)
#pragma unroll
      for (int ni = 0; ni < 4; ++ni) lred[w - 2][(mi * 4 + ni) * 64 + l] = acc[mi][ni];
  }
  __syncthreads();
  if (w < 2) {
#pragma unroll
    for (int mi = 0; mi < 4; ++mi)
#pragma unroll
      for (int ni = 0; ni < 4; ++ni) acc[mi][ni] += lred[w][(mi * 4 + ni) * 64 + l];
  }
  __syncthreads();
  if (w == 1) {
#pragma unroll
    for (int mi = 0; mi < 4; ++mi)
#pragma unroll
      for (int ni = 0; ni < 4; ++ni) lred[0][(mi * 4 + ni) * 64 + l] = acc[mi][ni];
  }
  __syncthreads();
  if (w == 0) {
    float* cb = cov + ((size_t)li * BH + bh) * 4096;
    float labs = 0.f, ldiag = 0.f;
#pragma unroll
    for (int mi = 0; mi < 4; ++mi)
#pragma unroll
      for (int ni = 0; ni < 4; ++ni) {
        acc[mi][ni] += lred[0][(mi * 4 + ni) * 64 + l];
        *(f32x4*)(cb + (size_t)(mi * 4 + ni) * 256 + l * 4) = acc[mi][ni];  // coalesced 1KB
#pragma unroll
        for (int r = 0; r < 4; ++r) {
          int d = 16 * mi + (l >> 4) * 4 + r;
          int c = 16 * ni + lr;
          float vv = acc[mi][ni][r];
          labs += fabsf(vv);
          if (d == c) ldiag += fabsf(vv);
        }
      }
#pragma unroll
    for (int off = 32; off > 0; off >>= 1) {
      labs += __shfl_xor(labs, off);
      ldiag += __shfl_xor(ldiag, off);
    }
    if (l == 0 && li > 0) {
      float lam = fminf(fmaxf(p_lambda[0], 0.f), 1.f);
      score[(size_t)bh * NLAG + (li - 1)] = lam * ldiag + (1.f - lam) * (labs - ldiag);
    }
  }
}

// ---------------- top-18: one wave per bh, register-resident argmax -----------
__global__ void k_topk(const float* __restrict__ score, int* __restrict__ sel,
                       float* __restrict__ wgt, const float* __restrict__ p_log_tau_lag) {
  const int bh = blockIdx.x;
  const int lane = threadIdx.x;        // 64 lanes = 1 wave
  float sc = score[(size_t)bh * NLAG + lane];
  float ts[KTOP];
  int ti[KTOP];
#pragma unroll
  for (int k = 0; k < KTOP; ++k) {
    float v = sc;
    int idx = lane;
#pragma unroll
    for (int off = 32; off > 0; off >>= 1) {
      float ov = __shfl_xor(v, off);
      int oi = __shfl_xor(idx, off);
      if (ov > v || (ov == v && oi < idx)) { v = ov; idx = oi; }
    }
    ts[k] = v;
    ti[k] = idx;
    if (lane == idx) sc = -3e38f;      // remove winner (tie -> lowest index, like lax.top_k)
  }
  const float tau_lag = fmaxf(expf(p_log_tau_lag[0]), 1e-4f);
  const float mx = ts[0];
  float e[KTOP];
  float sum = 0.f;
#pragma unroll
  for (int k = 0; k < KTOP; ++k) { e[k] = expf((ts[k] - mx) / tau_lag); sum += e[k]; }
  const float rs = 1.0f / sum;
  if (lane < KTOP) {
    sel[bh * KTOP + lane] = ti[lane];
    wgt[bh * KTOP + lane] = e[lane] * rs;
  }
}

// ---------------- softmax of 19 selected cov (fragment-linear in & out) -------
// Reads cov fragments coalesced; softmax in-register (ni regs x 16-lane shfl);
// writes attP fragment-linear: attP[(m*32+bh)*4096 + (ni*2+tc)*512 + l2*8 + j]
__global__ __launch_bounds__(256) void k_attsm(const float* __restrict__ cov, const int* __restrict__ sel,
                                               const float* __restrict__ wgt,
                                               u16* __restrict__ attP,
                                               const float* __restrict__ p_log_tau,
                                               const float* __restrict__ p_beta) {
  const int bh = blockIdx.x, m = blockIdx.y;
  const int slot = (m == 0) ? 0 : (1 + (sel[bh * KTOP + m - 1] & 63));
  const float beta = fminf(fmaxf(p_beta[0], 0.f), 1.f);
  const float smv = (m == 0) ? (1.f - beta) : (beta * wgt[bh * KTOP + m - 1]);
  const float itau = 1.f / fmaxf(expf(p_log_tau[0]), 1e-4f);
  const float* cb = cov + ((size_t)slot * BH + bh) * 4096;
  const int l = threadIdx.x & 63, wv = threadIdx.x >> 6;   // wv = mi
  const int g = l >> 4, lr = l & 15;
  f32x4 a[4];
#pragma unroll
  for (int ni = 0; ni < 4; ++ni)
    a[ni] = *(const f32x4*)(cb + (size_t)(wv * 4 + ni) * 256 + l * 4);
  // softmax over c per row d = 16*wv + 4g + r  (c lives in 4 ni-regs x 16 lanes)
  float ev[4][4];
#pragma unroll
  for (int r = 0; r < 4; ++r) {
    float vmax = a[0][r];
#pragma unroll
    for (int ni = 1; ni < 4; ++ni) vmax = fmaxf(vmax, a[ni][r]);
#pragma unroll
    for (int off = 8; off > 0; off >>= 1) vmax = fmaxf(vmax, __shfl_xor(vmax, off));
    float s = 0.f;
#pragma unroll
    for (int ni = 0; ni < 4; ++ni) { ev[ni][r] = expf((a[ni][r] - vmax) * itau); s += ev[ni][r]; }
#pragma unroll
    for (int off = 8; off > 0; off >>= 1) s += __shfl_xor(s, off);
    float inv = smv / s;
#pragma unroll
    for (int ni = 0; ni < 4; ++ni) ev[ni][r] *= inv;
  }
  // write attP: d = 16wv+4g+r -> tc = wv>>1, g2 = 2(wv&1)+(g>>1), j = 4(g&1)+r
  u16* th = attP + ((size_t)m * BH + bh) * 4096;
  const int tc = wv >> 1;
  const int l2 = 16 * (2 * (wv & 1) + (g >> 1)) + lr;
  const int jb = 4 * (g & 1);
#pragma unroll
  for (int ni = 0; ni < 4; ++ni) {
    ushort4 o4 = make_ushort4(bf16r(ev[ni][0]), bf16r(ev[ni][1]), bf16r(ev[ni][2]), bf16r(ev[ni][3]));
    *(ushort4*)(th + (size_t)(ni * 2 + tc) * 512 + l2 * 8 + jb) = o4;
  }
}

// ---------------- weighted contrib sum: m-split across waves + LDS reduce -----
__global__ __launch_bounds__(256) void k_contrib(const u16* __restrict__ V2,
                                                 const u16* __restrict__ attP,
                                                 const int* __restrict__ sel,
                                                 u16* __restrict__ oh) {
  const int tt = blockIdx.x;                 // 32-row t-tiles: 0..15
  const int bh = blockIdx.y;
  const int b_ = bh >> 3, h_ = bh & 7;
  const int t0 = tt * 32;
  const int tid = threadIdx.x, l = tid & 63, w = tid >> 6;
  const int lr = l & 15, lk = (l >> 4) * 8;
  __shared__ f32x4 lred[2][512];             // 16 KB
  f32x4 acc[2][4] = {};
  const u16* Vb = V2 + (size_t)bh * 65536;
  const int mstart[5] = {0, 5, 10, 15, 19};
  for (int m = mstart[w]; m < mstart[w + 1]; ++m) {
    const int lag = (m == 0) ? 0 : lag_of(sel[bh * KTOP + m - 1] & 63);
    const u16* ab = attP + ((size_t)m * BH + bh) * 4096;
#pragma unroll
    for (int ks = 0; ks < 2; ++ks) {
      const int kb2 = ks * 32 + lk;
      bf16x8 Bf[4];
#pragma unroll
      for (int ni = 0; ni < 4; ++ni)
        Bf[ni] = *(const bf16x8*)(ab + (size_t)(ni * 2 + ks) * 512 + l * 8);
#pragma unroll
      for (int mi = 0; mi < 2; ++mi) {
        const int ub = t0 + 16 * mi + 512 - lag + lr;
        bf16x8 A = *(const bf16x8*)(Vb + (size_t)ub * 64 + kb2);
#pragma unroll
        for (int ni = 0; ni < 4; ++ni)
          acc[mi][ni] = __builtin_amdgcn_mfma_f32_16x16x32_bf16(A, Bf[ni], acc[mi][ni], 0, 0, 0);
      }
    }
  }
  if (w >= 2) {
#pragma unroll
    for (int mi = 0; mi < 2; ++mi)
#pragma unroll
      for (int ni = 0; ni < 4; ++ni) lred[w - 2][(mi * 4 + ni) * 64 + l] = acc[mi][ni];
  }
  __syncthreads();
  if (w < 2) {
#pragma unroll
    for (int mi = 0; mi < 2; ++mi)
#pragma unroll
      for (int ni = 0; ni < 4; ++ni) acc[mi][ni] += lred[w][(mi * 4 + ni) * 64 + l];
  }
  __syncthreads();
  if (w == 1) {
#pragma unroll
    for (int mi = 0; mi < 2; ++mi)
#pragma unroll
      for (int ni = 0; ni < 4; ++ni) lred[0][(mi * 4 + ni) * 64 + l] = acc[mi][ni];
  }
  __syncthreads();
  if (w == 0) {
#pragma unroll
    for (int mi = 0; mi < 2; ++mi)
#pragma unroll
      for (int ni = 0; ni < 4; ++ni) {
        acc[mi][ni] += lred[0][(mi * 4 + ni) * 64 + l];
#pragma unroll
        for (int r = 0; r < 4; ++r) {
          int t = t0 + 16 * mi + (l >> 4) * 4 + r;
          int c = 16 * ni + lr;
          oh[((size_t)b_ * 512 + t) * 512 + h_ * 64 + c] = bf16r(acc[mi][ni][r]);
        }
      }
  }
}

// ---------------- final projection (MFMA, single bf16, 64-row m-tiles) --------
__global__ __launch_bounds__(256) void k_out(const u16* __restrict__ oh,
                                             const u16* __restrict__ WTh,
                                             const float* __restrict__ bo, float* __restrict__ out) {
  const u16* Bh_ = WTh + (size_t)3 * 262144;
  const int n0 = blockIdx.x * 64, m0 = blockIdx.y * 64;
  const int l = threadIdx.x & 63, w = threadIdx.x >> 6;
  const int lr = l & 15, lk = (l >> 4) * 8;
  const int arow = m0 + 16 * w + lr;
  f32x4 acc[4];
#pragma unroll
  for (int i = 0; i < 4; ++i) { float b = bo[n0 + 16 * i + lr]; acc[i] = (f32x4){b, b, b, b}; }
  for (int ks = 0; ks < 16; ++ks) {
    int kb2 = ks * 32 + lk;
    bf16x8 A = *(const bf16x8*)(oh + (size_t)arow * 512 + kb2);
#pragma unroll
    for (int i = 0; i < 4; ++i) {
      bf16x8 Bf = *(const bf16x8*)(Bh_ + (size_t)(n0 + 16 * i + lr) * 512 + kb2);
      acc[i] = __builtin_amdgcn_mfma_f32_16x16x32_bf16(A, Bf, acc[i], 0, 0, 0);
    }
  }
#pragma unroll
  for (int i = 0; i < 4; ++i)
#pragma unroll
    for (int r = 0; r < 4; ++r) {
      int m = m0 + 16 * w + (l >> 4) * 4 + r;
      int n = n0 + 16 * i + lr;
      out[(size_t)m * 512 + n] = acc[i][r];
    }
}

}  // namespace

extern "C" void kernel_launch(void* const* d_in, const int* in_sizes, int n_in,
                              void* d_out, int out_size, void* d_ws, size_t ws_size,
                              hipStream_t stream) {
  (void)in_sizes; (void)n_in; (void)out_size; (void)ws_size;
  const float* x  = (const float*)d_in[0];
  const float* Wq = (const float*)d_in[1];
  const float* bq = (const float*)d_in[2];
  const float* Wk = (const float*)d_in[3];
  const float* bk = (const float*)d_in[4];
  const float* Wv = (const float*)d_in[5];
  const float* bv = (const float*)d_in[6];
  const float* Wo = (const float*)d_in[7];
  const float* bo = (const float*)d_in[8];
  const float* p_log_tau     = (const float*)d_in[9];
  const float* p_lambda      = (const float*)d_in[10];
  const float* p_beta        = (const float*)d_in[11];
  const float* p_log_tau_lag = (const float*)d_in[12];

  char* ws = (char*)d_ws;
  const size_t MB = 1ull << 20;
  u16*   xh    = (u16*)(ws + 0 * MB);     // 2 MB
  u16*   xl    = (u16*)(ws + 2 * MB);     // 2 MB
  u16*   WTh   = (u16*)(ws + 4 * MB);     // 2 MB (q,k,v,o)
  u16*   WTl   = (u16*)(ws + 6 * MB);     // 2 MB
  u16*   QPh   = (u16*)(ws + 8 * MB);     // 2 MB  fragment-linear Q
  u16*   QPl   = (u16*)(ws + 10 * MB);    // 2 MB
  u16*   KT2   = (u16*)(ws + 12 * MB);    // 8 MB  [bh][64][1024][2] hi/lo interleaved
  u16*   V2    = (u16*)(ws + 20 * MB);    // 4 MB  [bh][1024][64]
  float* qf    = (float*)(ws + 24 * MB);  // 4 MB (dead after k_pack)
  float* kf    = (float*)(ws + 28 * MB);  // 4 MB (dead after k_pack)
  float* vf    = (float*)(ws + 32 * MB);  // 4 MB (dead after k_pack)
  u16*   attP  = (u16*)(ws + 24 * MB);    // 4.75 MB overlay on qf/kf (after k_pack)
  u16*   oh    = (u16*)(ws + 32 * MB);    // 2 MB overlay on vf (after k_pack)
  float* cov   = (float*)(ws + 36 * MB);  // 34 MB (fragment-linear)
  float* score = (float*)(ws + 70 * MB);          // 8 KB
  float* wgt   = (float*)(ws + 70 * MB + 16384);  // 2.3 KB
  int*   sel   = (int*)(ws + 70 * MB + 32768);    // 2.3 KB
  float* sinv  = (float*)(ws + 70 * MB + 49152);  // 16 KB [2][32][64]

  const dim3 blk(256);

  k_prep_x<<<dim3(1024), blk, 0, stream>>>(x, xh, xl);
  k_prep_w<<<dim3(8, 8, 4), blk, 0, stream>>>(Wq, Wk, Wv, Wo, WTh, WTl);
  k_qkv<<<dim3(8, 32, 3), blk, 0, stream>>>(xh, xl, WTh, WTl, bq, bk, bv, qf, kf, vf);
  k_ssq<<<dim3(32, 2), blk, 0, stream>>>(qf, kf, sinv);
  k_pack<<<dim3(8, 32), blk, 0, stream>>>(qf, kf, vf, sinv, QPh, QPl, KT2, V2);
  k_cov<<<dim3(2080), blk, 0, stream>>>(KT2, QPh, QPl, cov, score, p_lambda);
  k_topk<<<dim3(32), dim3(64), 0, stream>>>(score, sel, wgt, p_log_tau_lag);
  k_attsm<<<dim3(32, 19), blk, 0, stream>>>(cov, sel, wgt, attP, p_log_tau, p_beta);
  k_contrib<<<dim3(16, 32), blk, 0, stream>>>(V2, attP, sel, oh);
  k_out<<<dim3(8, 32), blk, 0, stream>>>(oh, WTh, bo, (float*)d_out);
}